// Round 9
// baseline (335.631 us; speedup 1.0000x reference)
//
#include <hip/hip_runtime.h>

#define TSEQ 1024
#define HID_ 1024
#define NH 8
#define DK 128
#define DV 128
#define ROWS 2048               // B*T
#define SZf (ROWS * HID_)       // floats per [2048,1024] matrix
#define LCH 64                  // scan chunk length
#define NCK 16                  // chunks per (b,h)
#define KSTR 136                // bf16 LDS stride for [64][128] tiles
#define ESTR 65

typedef __attribute__((ext_vector_type(8))) short short8;
typedef __attribute__((ext_vector_type(4))) float f32x4;
#define MFMA __builtin_amdgcn_mfma_f32_16x16x32_bf16

__device__ __forceinline__ float sig_(float x) { return 1.f / (1.f + __expf(-x)); }

__device__ __forceinline__ ushort f2bf(float f) {   // RNE f32->bf16
    unsigned int u = __builtin_bit_cast(unsigned int, f);
    u += 0x7FFF + ((u >> 16) & 1);
    return (ushort)(u >> 16);
}
__device__ __forceinline__ unsigned int pk2(float lo, float hi) {
    return (unsigned int)f2bf(lo) | ((unsigned int)f2bf(hi) << 16);
}

// ---------------- x -> bf16 ----------------
__global__ __launch_bounds__(256)
void k_x2bf(const float* __restrict__ x, ushort* __restrict__ xb)
{
    const size_t i8 = (size_t)blockIdx.x * 256 + threadIdx.x;   // grid 1024
    float4 v0 = *(const float4*)(x + i8 * 8);
    float4 v1 = *(const float4*)(x + i8 * 8 + 4);
    uint4 o;
    o.x = pk2(v0.x, v0.y); o.y = pk2(v0.z, v0.w);
    o.z = pk2(v1.x, v1.y); o.w = pk2(v1.z, v1.w);
    *(uint4*)(xb + i8 * 8) = o;
}

// ---------------- weight transpose+convert: W f32 [K][N] -> WT bf16 [N][K] ----
__global__ __launch_bounds__(256)
void k_wT(const float* __restrict__ s0, const float* __restrict__ s1,
          const float* __restrict__ s2, const float* __restrict__ s3,
          ushort* __restrict__ dst)
{
    const int z = blockIdx.z;
    const float* W = (z == 0) ? s0 : (z == 1) ? s1 : (z == 2) ? s2 : s3;
    ushort* WT = dst + (size_t)z * (1024 * 1024);
    __shared__ float t[64][65];
    const int n0 = blockIdx.x * 64, k0 = blockIdx.y * 64;
    const int rr = threadIdx.x >> 4, cc = threadIdx.x & 15;
#pragma unroll
    for (int i = 0; i < 4; ++i) {
        const int row = i * 16 + rr;
        float4 v = *(const float4*)(W + (size_t)(k0 + row) * 1024 + n0 + cc * 4);
        t[row][cc * 4 + 0] = v.x; t[row][cc * 4 + 1] = v.y;
        t[row][cc * 4 + 2] = v.z; t[row][cc * 4 + 3] = v.w;
    }
    __syncthreads();
#pragma unroll
    for (int i = 0; i < 4; ++i) {
        const int n = i * 16 + rr;
        const int kc = cc * 4;
        ushort4 o;
        o.x = f2bf(t[kc + 0][n]); o.y = f2bf(t[kc + 1][n]);
        o.z = f2bf(t[kc + 2][n]); o.w = f2bf(t[kc + 3][n]);
        *(ushort4*)(WT + (size_t)(n0 + n) * 1024 + k0 + kc) = o;
    }
}

// ------------- bf16 MFMA GEMM: C = A(bf16 [M][K]) x BT(bf16 [N][K]) -------------
#define LDSB 40
__device__ __forceinline__ void gemm_tile_mfma(const ushort* __restrict__ A,
                                               const ushort* __restrict__ BT,
                                               float* __restrict__ C,
                                               int brow, int bcol)
{
    __shared__ ushort As[128 * LDSB];
    __shared__ ushort Bs[128 * LDSB];
    const int tid  = threadIdx.x;
    const int lane = tid & 63;
    const int wv   = tid >> 6;
    const int wm   = (wv >> 1) * 64;
    const int wn   = (wv & 1) * 64;
    const int l15  = lane & 15;
    const int k8   = (lane >> 4) * 8;
    const int srow = tid >> 1;
    const int skh  = (tid & 1) * 16;

    f32x4 acc[4][4];
#pragma unroll
    for (int i = 0; i < 4; ++i)
#pragma unroll
        for (int j = 0; j < 4; ++j)
#pragma unroll
            for (int e = 0; e < 4; ++e) acc[i][j][e] = 0.f;

    const ushort* arow = A  + (size_t)(brow + srow) * 1024 + skh;
    const ushort* brp  = BT + (size_t)(bcol + srow) * 1024 + skh;
    ushort* asw = As + srow * LDSB + skh;
    ushort* bsw = Bs + srow * LDSB + skh;

    for (int k0 = 0; k0 < 1024; k0 += 32) {
        uint4 a0 = *(const uint4*)(arow + k0);
        uint4 a1 = *(const uint4*)(arow + k0 + 8);
        uint4 b0 = *(const uint4*)(brp + k0);
        uint4 b1 = *(const uint4*)(brp + k0 + 8);
        __syncthreads();
        *(uint4*)(asw)     = a0;
        *(uint4*)(asw + 8) = a1;
        *(uint4*)(bsw)     = b0;
        *(uint4*)(bsw + 8) = b1;
        __syncthreads();
        short8 af[4], bf[4];
#pragma unroll
        for (int i = 0; i < 4; ++i)
            af[i] = *(const short8*)(As + (wm + i * 16 + l15) * LDSB + k8);
#pragma unroll
        for (int j = 0; j < 4; ++j)
            bf[j] = *(const short8*)(Bs + (wn + j * 16 + l15) * LDSB + k8);
#pragma unroll
        for (int i = 0; i < 4; ++i)
#pragma unroll
            for (int j = 0; j < 4; ++j)
                acc[i][j] = MFMA(af[i], bf[j], acc[i][j], 0, 0, 0);
    }
    const int l4 = lane >> 4;
#pragma unroll
    for (int i = 0; i < 4; ++i)
#pragma unroll
        for (int j = 0; j < 4; ++j)
#pragma unroll
            for (int r = 0; r < 4; ++r)
                C[(size_t)(brow + wm + i * 16 + l4 * 4 + r) * 1024 +
                  bcol + wn + j * 16 + l15] = acc[i][j][r];
}

__global__ __launch_bounds__(256)
void k_gemm4(const ushort* __restrict__ A, const ushort* __restrict__ WT,
             float* __restrict__ Cbase)
{
    const ushort* BT = WT + (size_t)blockIdx.z * (1024 * 1024);
    float* C = Cbase + (size_t)blockIdx.z * SZf;
    gemm_tile_mfma(A, BT, C, blockIdx.y * 128, blockIdx.x * 128);
}

__global__ __launch_bounds__(256)
void k_gemm1(const ushort* __restrict__ A, const ushort* __restrict__ BT,
             float* __restrict__ C)
{
    gemm_tile_mfma(A, BT, C, blockIdx.y * 128, blockIdx.x * 128);
}

// -------- alpha/beta small GEMM + sigmoid; writes TRANSPOSED [bh][t] --------
__global__ __launch_bounds__(64)
void k_ab(const float* __restrict__ x, const float* __restrict__ Wa,
          const float* __restrict__ ba, const float* __restrict__ Wb,
          const float* __restrict__ bb, float* __restrict__ aT,
          float* __restrict__ bT)
{
    const int r = blockIdx.x;
    const int lane = threadIdx.x;
    const int b = r >> 10, t = r & 1023;
    const float* xr = x + (size_t)r * HID_;
    float acc[16];
#pragma unroll
    for (int n = 0; n < 16; ++n) acc[n] = 0.f;
    for (int c = lane; c < HID_; c += 64) {
        const float xv = xr[c];
        const float* wa = Wa + c * 8;
        const float* wb = Wb + c * 8;
#pragma unroll
        for (int n = 0; n < 8; ++n) {
            acc[n]     = fmaf(xv, wa[n], acc[n]);
            acc[8 + n] = fmaf(xv, wb[n], acc[8 + n]);
        }
    }
#pragma unroll
    for (int n = 0; n < 16; ++n) {
#pragma unroll
        for (int m = 32; m; m >>= 1) acc[n] += __shfl_xor(acc[n], m);
    }
    if (lane < 8) {
        aT[(size_t)(b * 8 + lane) * TSEQ + t] = sig_(acc[lane] + ba[lane]);
        bT[(size_t)(b * 8 + lane) * TSEQ + t] = sig_(acc[8 + lane] + bb[lane]);
    }
}

// -------- causal depthwise conv K=4 + SiLU (+scale), in-place, T-parallel ----
__global__ __launch_bounds__(256)
void k_conv_save(const float* __restrict__ q, const float* __restrict__ k,
                 const float* __restrict__ v, float* __restrict__ scr)
{
    const int z = blockIdx.z, b = blockIdx.y, j = blockIdx.x + 1;
    const float* y = (z == 0) ? q : (z == 1) ? k : v;
    float* d = scr + ((size_t)(z * 2 + b) * 15 + (j - 1)) * 3 * 1024;
    const float* s = y + ((size_t)b * TSEQ + j * 64 - 3) * HID_;
    for (int i = threadIdx.x; i < 3 * 1024; i += 256)
        d[i] = s[i];
}

__global__ __launch_bounds__(256)
void k_conv_apply(float* __restrict__ q, float* __restrict__ k, float* __restrict__ v,
                  const float* __restrict__ scr,
                  const float* __restrict__ wq, const float* __restrict__ bq,
                  const float* __restrict__ wk, const float* __restrict__ bk,
                  const float* __restrict__ wv, const float* __restrict__ bv)
{
    const int z = blockIdx.z, b = blockIdx.y;
    const int j = blockIdx.x >> 2, cg = blockIdx.x & 3;
    float* y          = (z == 0) ? q  : (z == 1) ? k  : v;
    const float* w    = (z == 0) ? wq : (z == 1) ? wk : wv;
    const float* bias = (z == 0) ? bq : (z == 1) ? bk : bv;
    const float scale = (z == 1) ? 0.08838834764831845f : 1.f;
    const int c = cg * 256 + threadIdx.x;
    const float w0 = w[c * 4], w1 = w[c * 4 + 1], w2 = w[c * 4 + 2], w3 = w[c * 4 + 3];
    const float bs = bias[c];
    float y0 = 0.f, y1 = 0.f, y2 = 0.f;
    if (j > 0) {
        const float* s = scr + ((size_t)(z * 2 + b) * 15 + (j - 1)) * 3 * 1024 + c;
        y0 = s[0]; y1 = s[1024]; y2 = s[2048];
    }
    float* yp = y + ((size_t)b * TSEQ + j * 64) * HID_ + c;
#pragma unroll 4
    for (int t = 0; t < 64; ++t) {
        float y3  = yp[(size_t)t * HID_];
        float acc = fmaf(w0, y0, fmaf(w1, y1, fmaf(w2, y2, fmaf(w3, y3, bs))));
        float sv  = acc * sig_(acc) * scale;
        yp[(size_t)t * HID_] = sv;
        y0 = y1; y1 = y2; y2 = y3;
    }
}

// ---------- k_stage: pre-format K,Q (bf16, chunk layout) + KT per chunk ------
__global__ __launch_bounds__(256)
void k_stage(const float* __restrict__ klin, const float* __restrict__ qlin,
             ushort* __restrict__ Kst, ushort* __restrict__ Qst,
             ushort* __restrict__ KTst)
{
    const int cid = blockIdx.x;          // bh*16 + c
    const int bh = cid >> 4, c = cid & 15;
    const int b = bh >> 3, h = bh & 7;
    const int tid = threadIdx.x;
    const int t0 = c * LCH;
    __shared__ ushort Kl[64 * KSTR];
    const float* kb = klin + ((size_t)b * TSEQ + t0) * HID_ + h * DK;
    const float* qb = qlin + ((size_t)b * TSEQ + t0) * HID_ + h * DK;
    const size_t go = (size_t)cid * 8192;
#pragma unroll
    for (int j = 0; j < 8; ++j) {
        const int i4 = tid + j * 256;
        const int row = i4 >> 5, c4 = i4 & 31;
        float4 kv = *(const float4*)(kb + (size_t)row * HID_ + c4 * 4);
        float4 qv = *(const float4*)(qb + (size_t)row * HID_ + c4 * 4);
        uint2 kp; kp.x = pk2(kv.x, kv.y); kp.y = pk2(kv.z, kv.w);
        uint2 qp; qp.x = pk2(qv.x, qv.y); qp.y = pk2(qv.z, qv.w);
        *(uint2*)(Kst + go + row * 128 + c4 * 4) = kp;
        *(uint2*)(Qst + go + row * 128 + c4 * 4) = qp;
        *(uint2*)(Kl + row * KSTR + c4 * 4) = kp;
    }
    __syncthreads();
#pragma unroll
    for (int j = 0; j < 4; ++j) {                 // KT [dk][t]
        const int o8 = tid + j * 256;
        const int dk = o8 >> 3, tt = (o8 & 7) * 8;
        ushort tmp[8];
#pragma unroll
        for (int e = 0; e < 8; ++e) tmp[e] = Kl[(tt + e) * KSTR + dk];
        *(uint4*)(KTst + go + dk * 64 + tt) = *(uint4*)tmp;
    }
}

// ============ kernel P: per-chunk parallel precompute (M, G, decays) =========
__global__ __launch_bounds__(256)
void k_prep(const ushort* __restrict__ Kst, const ushort* __restrict__ Qst,
            const float* __restrict__ aT, const float* __restrict__ bT,
            ushort* __restrict__ Mg, ushort* __restrict__ Gg,
            float* __restrict__ pug, float* __restrict__ pog,
            float* __restrict__ cg, float* __restrict__ dtotg)
{
    const int cid = blockIdx.x;
    const int bh = cid >> 4, c = cid & 15;
    const int tid = threadIdx.x;
    const int t0 = c * LCH;

    __shared__ ushort Kb[64 * KSTR], Qb[64 * KSTR];
    __shared__ float Ef[64 * ESTR];
    __shared__ float Mf[64 * ESTR];
    __shared__ float cums[64], bv[64];

    if (tid < 64) {
        const float a = aT[(size_t)bh * TSEQ + t0 + tid];
        bv[tid] = bT[(size_t)bh * TSEQ + t0 + tid];
        float cs = __logf(a);
#pragma unroll
        for (int d = 1; d < 64; d <<= 1) {
            float pv = __shfl_up(cs, d);
            if (tid >= d) cs += pv;
        }
        cums[tid] = cs;
    }
    const size_t go = (size_t)cid * 8192;
#pragma unroll
    for (int j = 0; j < 4; ++j) {
        const int i16 = tid + j * 256;
        const int row = i16 >> 4, col = (i16 & 15) * 8;
        *(uint4*)(Kb + row * KSTR + col) = *(const uint4*)(Kst + go + i16 * 8);
        *(uint4*)(Qb + row * KSTR + col) = *(const uint4*)(Qst + go + i16 * 8);
    }
    __syncthreads();

    const int wv = tid >> 6, l = tid & 63, l15 = l & 15, lq = l >> 4;
    const int k8o = lq * 8;
    f32x4 accK[4], accQ4[4];
#pragma unroll
    for (int j = 0; j < 4; ++j) {
        accK[j] = f32x4{0.f, 0.f, 0.f, 0.f};
        accQ4[j] = f32x4{0.f, 0.f, 0.f, 0.f};
    }
#pragma unroll
    for (int kk = 0; kk < 4; ++kk) {
        short8 aK = *(const short8*)(Kb + (wv * 16 + l15) * KSTR + kk * 32 + k8o);
        short8 aQ = *(const short8*)(Qb + (wv * 16 + l15) * KSTR + kk * 32 + k8o);
#pragma unroll
        for (int js = 0; js < 4; ++js) {
            short8 bK = *(const short8*)(Kb + (js * 16 + l15) * KSTR + kk * 32 + k8o);
            accK[js]  = MFMA(aK, bK, accK[js], 0, 0, 0);
            accQ4[js] = MFMA(aQ, bK, accQ4[js], 0, 0, 0);
        }
    }
    ushort* Gc = Gg + (size_t)cid * 4096;
#pragma unroll
    for (int js = 0; js < 4; ++js) {
#pragma unroll
        for (int r = 0; r < 4; ++r) {
            const int t = wv * 16 + lq * 4 + r;
            const int s = js * 16 + l15;
            const float cp = (t > 0) ? cums[t - 1] : 0.f;
            Ef[t * ESTR + s] = (s < t) ? __expf(cp - cums[s]) * accK[js][r] : 0.f;
            const float gv = (s <= t) ? __expf(cums[t] - cums[s]) * accQ4[js][r] : 0.f;
            Gc[t * 64 + s] = f2bf(gv);
        }
    }
    __syncthreads();

    if (tid < 64) {                     // M-solve: lane s owns column s
        const int s = tid;
        for (int r = 0; r < 64; ++r) Mf[r * ESTR + s] = 0.f;
        Mf[s * ESTR + s] = bv[s];
        for (int t = 1; t < 64; ++t) {
            float s0 = 0.f, s1 = 0.f;
            int r = 0;
            for (; r + 1 < t; r += 2) {
                s0 = fmaf(Ef[t * ESTR + r],     Mf[r * ESTR + s],       s0);
                s1 = fmaf(Ef[t * ESTR + r + 1], Mf[(r + 1) * ESTR + s], s1);
            }
            if (r < t) s0 = fmaf(Ef[t * ESTR + r], Mf[r * ESTR + s], s0);
            if (s < t) Mf[t * ESTR + s] = -bv[t] * (s0 + s1);
        }
    }
    __syncthreads();
    ushort* Mc = Mg + (size_t)cid * 4096;
#pragma unroll
    for (int j = 0; j < 16; ++j) {
        const int e = tid + j * 256;
        Mc[e] = f2bf(Mf[(e >> 6) * ESTR + (e & 63)]);
    }
    if (tid < 64) {
        const float cp = (tid > 0) ? cums[tid - 1] : 0.f;
        pug[cid * 64 + tid] = __expf(cp);
        pog[cid * 64 + tid] = __expf(cums[tid]);
        cg [cid * 64 + tid] = __expf(cums[63] - cums[tid]);
        if (tid == 0) dtotg[cid] = __expf(cums[63]);
    }
}

// ===== kernel S: wave-local chunk pipeline; waves 0-1 compute, 2-3 stage =====
// Each compute wave owns 16 dv rows x all 64 t x all 128 dk (accS[8]).
// Entire S->U->Y->W->O->S chain is within-wave (no inter-phase barriers);
// 2 barriers/chunk total. Stage waves prefetch chunk c+1 under chunk c compute.
__global__ __launch_bounds__(256)
void k_scan2(const ushort* __restrict__ Kst, const ushort* __restrict__ Qst,
             const ushort* __restrict__ KTst, const float* __restrict__ vlin,
             const ushort* __restrict__ Mg, const ushort* __restrict__ Gg,
             const float* __restrict__ pug, const float* __restrict__ pog,
             const float* __restrict__ cg, const float* __restrict__ dtotg,
             float* __restrict__ o)
{
    const int blk = blockIdx.x;          // bh*4 + rb
    const int bh = blk >> 2, rb = blk & 3;
    const int b = bh >> 3, h = bh & 7;
    const int tid = threadIdx.x;
    const int wv = tid >> 6, l = tid & 63, l15 = l & 15, lq = l >> 4;
    const int k8o = lq * 8;
    const int st = tid - 128;            // stage-thread index (wv>=2)

    __shared__ ushort Kb[64 * KSTR], Qb[64 * KSTR];
    __shared__ ushort KTb[128 * 72];
    __shared__ float  Vtf[32 * 72];
    __shared__ ushort Mb[64 * 72], Gb[64 * 72];
    __shared__ ushort Shb[32 * KSTR], Slb[32 * KSTR];
    __shared__ ushort Yb[32 * 72], Wb[32 * 72], Wcb[32 * 72];
    __shared__ float  Otf[64 * 36];
    __shared__ float  puv[64], pov[64], cv2[64], dts[1];

    f32x4 accS[8];
#pragma unroll
    for (int m = 0; m < 8; ++m) accS[m] = f32x4{0.f, 0.f, 0.f, 0.f};

    const float* vbase = vlin + (size_t)b * TSEQ * HID_ + h * DV + rb * 32;
    float* obase = o + (size_t)bh * TSEQ * DV + rb * 32;

    // stage-wave prefetch registers (dead on compute waves)
    uint4 rk[8], rq[8], rkt[8], rm[4], rg[4];
    float4 rv[4];
    float rpu = 0.f, rpo = 0.f, rcv = 0.f, rdt = 0.f;

    auto LOADC = [&](int cc) {
        const int cid = bh * 16 + cc;
        const size_t go = (size_t)cid * 8192;
#pragma unroll
        for (int j = 0; j < 8; ++j) {
            const int i16 = st + j * 128;
            rk[j]  = *(const uint4*)(Kst  + go + i16 * 8);
            rq[j]  = *(const uint4*)(Qst  + go + i16 * 8);
            rkt[j] = *(const uint4*)(KTst + go + i16 * 8);
        }
#pragma unroll
        for (int j = 0; j < 4; ++j) {
            const int i8 = st + j * 128;
            rm[j] = *(const uint4*)(Mg + (size_t)cid * 4096 + i8 * 8);
            rg[j] = *(const uint4*)(Gg + (size_t)cid * 4096 + i8 * 8);
            rv[j] = *(const float4*)(vbase + (size_t)(cc * LCH + (i8 >> 3)) * HID_ + (i8 & 7) * 4);
        }
        if (st < 64) {
            rpu = pug[cid * 64 + st];
            rpo = pog[cid * 64 + st];
            rcv = cg [cid * 64 + st];
            if (st == 0) rdt = dtotg[cid];
        }
    };
    auto WRITEC = [&]() {
#pragma unroll
        for (int j = 0; j < 8; ++j) {
            const int i16 = st + j * 128;
            *(uint4*)(Kb  + (i16 >> 4) * KSTR + (i16 & 15) * 8) = rk[j];
            *(uint4*)(Qb  + (i16 >> 4) * KSTR + (i16 & 15) * 8) = rq[j];
            *(uint4*)(KTb + (i16 >> 3) * 72   + (i16 & 7) * 8)  = rkt[j];
        }
#pragma unroll
        for (int j = 0; j < 4; ++j) {
            const int i8 = st + j * 128;
            *(uint4*)(Mb + (i8 >> 3) * 72 + (i8 & 7) * 8) = rm[j];
            *(uint4*)(Gb + (i8 >> 3) * 72 + (i8 & 7) * 8) = rg[j];
            const int row = i8 >> 3, c4 = i8 & 7;
            Vtf[(c4 * 4 + 0) * 72 + row] = rv[j].x;
            Vtf[(c4 * 4 + 1) * 72 + row] = rv[j].y;
            Vtf[(c4 * 4 + 2) * 72 + row] = rv[j].z;
            Vtf[(c4 * 4 + 3) * 72 + row] = rv[j].w;
        }
        if (st < 64) {
            puv[st] = rpu; pov[st] = rpo; cv2[st] = rcv;
            if (st == 0) dts[0] = rdt;
        }
    };

    if (wv >= 2) { LOADC(0); WRITEC(); }
    __syncthreads();

    for (int c = 0; c < NCK; ++c) {
        const int t0 = c * LCH;
        if (wv >= 2) {
            if (c + 1 < NCK) LOADC(c + 1);      // in flight through compute
        } else {
            // ---- B: state -> LDS hi/lo bf16 (wave-local rows)
#pragma unroll
            for (int m = 0; m < 8; ++m) {
#pragma unroll
                for (int r = 0; r < 4; ++r) {
                    const int dv = wv * 16 + lq * 4 + r;
                    const int dk = m * 16 + l15;
                    const float sv = accS[m][r];
                    const ushort hi = f2bf(sv);
                    const float hf = __builtin_bit_cast(float, ((unsigned)hi) << 16);
                    Shb[dv * KSTR + dk] = hi;
                    Slb[dv * KSTR + dk] = f2bf(sv - hf);
                }
            }
            // ---- C: U = S.K^T, UQ = S.Q^T (compensated), all 4 t-tiles
            f32x4 accU[4], accQ[4];
#pragma unroll
            for (int jj = 0; jj < 4; ++jj) {
                accU[jj] = f32x4{0.f, 0.f, 0.f, 0.f};
                accQ[jj] = f32x4{0.f, 0.f, 0.f, 0.f};
            }
#pragma unroll
            for (int kk = 0; kk < 4; ++kk) {
                short8 ah = *(const short8*)(Shb + (wv * 16 + l15) * KSTR + kk * 32 + k8o);
                short8 al = *(const short8*)(Slb + (wv * 16 + l15) * KSTR + kk * 32 + k8o);
#pragma unroll
                for (int jj = 0; jj < 4; ++jj) {
                    short8 bk = *(const short8*)(Kb + (jj * 16 + l15) * KSTR + kk * 32 + k8o);
                    short8 bq = *(const short8*)(Qb + (jj * 16 + l15) * KSTR + kk * 32 + k8o);
                    accU[jj] = MFMA(ah, bk, accU[jj], 0, 0, 0);
                    accU[jj] = MFMA(al, bk, accU[jj], 0, 0, 0);
                    accQ[jj] = MFMA(ah, bq, accQ[jj], 0, 0, 0);
                    accQ[jj] = MFMA(al, bq, accQ[jj], 0, 0, 0);
                }
            }
            // ---- D: Y = V^T - pu (.) U  (wave-local rows)
#pragma unroll
            for (int jj = 0; jj < 4; ++jj) {
                const int t = jj * 16 + l15;
                const float pu = puv[t];
#pragma unroll
                for (int r = 0; r < 4; ++r) {
                    const int dv = wv * 16 + lq * 4 + r;
                    Yb[dv * 72 + t] = f2bf(Vtf[dv * 72 + t] - pu * accU[jj][r]);
                }
            }
            // ---- E: W = Y x M
            f32x4 accW[4];
#pragma unroll
            for (int jj = 0; jj < 4; ++jj) accW[jj] = f32x4{0.f, 0.f, 0.f, 0.f};
#pragma unroll
            for (int kk = 0; kk < 2; ++kk) {
                short8 ay = *(const short8*)(Yb + (wv * 16 + l15) * 72 + kk * 32 + k8o);
#pragma unroll
                for (int jj = 0; jj < 4; ++jj) {
                    short8 bm = *(const short8*)(Mb + (jj * 16 + l15) * 72 + kk * 32 + k8o);
                    accW[jj] = MFMA(ay, bm, accW[jj], 0, 0, 0);
                }
            }
#pragma unroll
            for (int jj = 0; jj < 4; ++jj) {
                const int t = jj * 16 + l15;
                const float cvt = cv2[t];
#pragma unroll
                for (int r = 0; r < 4; ++r) {
                    const int dv = wv * 16 + lq * 4 + r;
                    const float wvl = accW[jj][r];
                    Wb[dv * 72 + t]  = f2bf(wvl);
                    Wcb[dv * 72 + t] = f2bf(wvl * cvt);
                }
            }
            // ---- F: O = po (.) UQ + G W
            f32x4 accO[4];
#pragma unroll
            for (int jj = 0; jj < 4; ++jj) accO[jj] = f32x4{0.f, 0.f, 0.f, 0.f};
#pragma unroll
            for (int kk = 0; kk < 2; ++kk) {
                short8 aw = *(const short8*)(Wb + (wv * 16 + l15) * 72 + kk * 32 + k8o);
#pragma unroll
                for (int jj = 0; jj < 4; ++jj) {
                    short8 bg = *(const short8*)(Gb + (jj * 16 + l15) * 72 + kk * 32 + k8o);
                    accO[jj] = MFMA(aw, bg, accO[jj], 0, 0, 0);
                }
            }
#pragma unroll
            for (int jj = 0; jj < 4; ++jj) {
                const int t = jj * 16 + l15;
                const float po = pov[t];
#pragma unroll
                for (int r = 0; r < 4; ++r) {
                    const int dv = wv * 16 + lq * 4 + r;
                    Otf[t * 36 + dv] = po * accQ[jj][r] + accO[jj][r];
                }
            }
            // ---- G: S = dtot*S + Wc x K (over s), all 8 dk-tiles
            const float dt = dts[0];
#pragma unroll
            for (int m = 0; m < 8; ++m)
#pragma unroll
                for (int r = 0; r < 4; ++r) accS[m][r] *= dt;
#pragma unroll
            for (int kk = 0; kk < 2; ++kk) {
                short8 aw = *(const short8*)(Wcb + (wv * 16 + l15) * 72 + kk * 32 + k8o);
#pragma unroll
                for (int m = 0; m < 8; ++m) {
                    short8 bk = *(const short8*)(KTb + (m * 16 + l15) * 72 + kk * 32 + k8o);
                    accS[m] = MFMA(aw, bk, accS[m], 0, 0, 0);
                }
            }
        }
        __syncthreads();      // Otf ready; staged bufs done being read
        if (wv >= 2) {
            // ---- H: coalesced O store (from Otf)
#pragma unroll
            for (int j = 0; j < 4; ++j) {
                const int i4 = st + j * 128;
                const int row = i4 >> 3, c4 = i4 & 7;
                float4 ov = *(const float4*)(Otf + row * 36 + c4 * 4);
                *(float4*)(obase + (size_t)(t0 + row) * DV + c4 * 4) = ov;
            }
            if (c + 1 < NCK) WRITEC();          // land next chunk
        }
        __syncthreads();
    }
}

// ---------------- LayerNorm(Dv) + sigmoid gate -> bf16 ----------------
__global__ __launch_bounds__(256)
void k_ln_gate(const float* __restrict__ o, const float* __restrict__ g_lin,
               const float* __restrict__ ln_g, const float* __restrict__ ln_b,
               ushort* __restrict__ ogb)
{
    const int idx  = blockIdx.x * 4 + (threadIdx.x >> 6);
    const int lane = threadIdx.x & 63;
    const int h  = idx & 7;
    const int bt = idx >> 3;
    const int b  = bt >> 10;
    const int t  = bt & 1023;
    const float* op = o + ((size_t)(b * NH + h) * TSEQ + t) * DV;
    float2 xv = ((const float2*)op)[lane];
    float s = xv.x + xv.y;
#pragma unroll
    for (int m = 32; m; m >>= 1) s += __shfl_xor(s, m);
    const float mu = s * (1.f / 128.f);
    const float d0 = xv.x - mu, d1 = xv.y - mu;
    float v = d0 * d0 + d1 * d1;
#pragma unroll
    for (int m = 32; m; m >>= 1) v += __shfl_xor(v, m);
    const float inv = rsqrtf(v * (1.f / 128.f) + 1e-5f);
    const int d = lane * 2;
    const float* gp = g_lin + (size_t)bt * HID_ + h * DV;
    const float g0 = sig_(gp[d]), g1 = sig_(gp[d + 1]);
    const float y0 = (d0 * inv * ln_g[d]     + ln_b[d])     * g0;
    const float y1 = (d1 * inv * ln_g[d + 1] + ln_b[d + 1]) * g1;
    *(uint*)(ogb + (size_t)bt * HID_ + h * DV + d) = pk2(y0, y1);
}

extern "C" void kernel_launch(void* const* d_in, const int* in_sizes, int n_in,
                              void* d_out, int out_size, void* d_ws, size_t ws_size,
                              hipStream_t stream)
{
    const float* x   = (const float*)d_in[0];
    const float* Wq  = (const float*)d_in[1];
    const float* Wk  = (const float*)d_in[2];
    const float* Wv  = (const float*)d_in[3];
    const float* cqw = (const float*)d_in[4];
    const float* cqb = (const float*)d_in[5];
    const float* ckw = (const float*)d_in[6];
    const float* ckb = (const float*)d_in[7];
    const float* cvw = (const float*)d_in[8];
    const float* cvb = (const float*)d_in[9];
    const float* Wa  = (const float*)d_in[10];
    const float* ba  = (const float*)d_in[11];
    const float* Wb  = (const float*)d_in[12];
    const float* bb  = (const float*)d_in[13];
    const float* Wg  = (const float*)d_in[14];
    const float* Wo  = (const float*)d_in[15];
    const float* lng = (const float*)d_in[16];
    const float* lnb = (const float*)d_in[17];
    float* out = (float*)d_out;
    float* ws  = (float*)d_ws;

    float* q_lin = ws;                       // f32; dead after k_stage; ogb reuses
    float* k_lin = ws + 1 * (size_t)SZf;     // f32; dead after k_stage; WoT reuses
    float* v_lin = ws + 2 * (size_t)SZf;
    float* g_lin = ws + 3 * (size_t)SZf;
    float* o_buf = ws + 4 * (size_t)SZf;     // WT4 -> conv scratch -> scan out
    float* aT    = ws + 5 * (size_t)SZf;
    float* bT    = aT + 16 * TSEQ;
    float* pug   = bT + 16 * TSEQ;
    float* pog   = pug + 256 * 64;
    float* cgd   = pog + 256 * 64;
    float* dtg   = cgd + 256 * 64;           // 256 floats

    float*  tail = ws + 5 * (size_t)SZf + 131072;
    ushort* Kst  = (ushort*)tail;                    // 4MB
    ushort* Qst  = Kst + (size_t)256 * 8192;         // 4MB
    ushort* xbf  = Qst + (size_t)256 * 8192;         // 4MB

    ushort* WT4 = (ushort*)o_buf;            // dead after gemm4
    ushort* WoT = (ushort*)k_lin;            // written after k_stage
    ushort* ogb = (ushort*)q_lin;            // bf16 LN output (4MB)
    ushort* Mg  = (ushort*)out;              // 2MB
    ushort* Gg  = Mg + (size_t)256 * 4096;   // 2MB
    ushort* KTst = Gg + (size_t)256 * 4096;  // 4MB -> fills d_out exactly

    k_x2bf<<<1024, 256, 0, stream>>>(x, xbf);
    k_wT<<<dim3(16, 16, 4), 256, 0, stream>>>(Wq, Wk, Wv, Wg, WT4);
    k_gemm4<<<dim3(8, 16, 4), 256, 0, stream>>>(xbf, WT4, ws);
    k_ab<<<ROWS, 64, 0, stream>>>(x, Wa, ba, Wb, bb, aT, bT);
    k_conv_save<<<dim3(15, 2, 3), 256, 0, stream>>>(q_lin, k_lin, v_lin, o_buf);
    k_conv_apply<<<dim3(64, 2, 3), 256, 0, stream>>>(q_lin, k_lin, v_lin, o_buf,
                                                     cqw, cqb, ckw, ckb, cvw, cvb);
    k_stage<<<256, 256, 0, stream>>>(k_lin, q_lin, Kst, Qst, KTst);
    k_prep<<<256, 256, 0, stream>>>(Kst, Qst, aT, bT, Mg, Gg, pug, pog, cgd, dtg);
    k_wT<<<dim3(16, 16, 1), 256, 0, stream>>>(Wo, Wo, Wo, Wo, WoT);
    k_scan2<<<64, 256, 0, stream>>>(Kst, Qst, KTst, v_lin, Mg, Gg,
                                    pug, pog, cgd, dtg, o_buf);
    k_ln_gate<<<4096, 256, 0, stream>>>(o_buf, g_lin, lng, lnb, ogb);
    k_gemm1<<<dim3(8, 16), 256, 0, stream>>>(ogb, WoT, out);
}

// Round 10
// 237.123 us; speedup vs baseline: 1.4154x; 1.4154x over previous
//
#include <hip/hip_runtime.h>

#define TSEQ 1024
#define HID_ 1024
#define NH 8
#define DK 128
#define DV 128
#define ROWS 2048               // B*T
#define SZf (ROWS * HID_)       // floats per [2048,1024] matrix
#define LCH 64                  // scan chunk length
#define NCK 16                  // chunks per (b,h)
#define KSTR 136                // bf16 LDS stride for [64][128] tiles
#define ESTR 65

typedef __attribute__((ext_vector_type(8))) short short8;
typedef __attribute__((ext_vector_type(4))) float f32x4;
#define MFMA __builtin_amdgcn_mfma_f32_16x16x32_bf16

__device__ __forceinline__ float sig_(float x) { return 1.f / (1.f + __expf(-x)); }

__device__ __forceinline__ ushort f2bf(float f) {   // RNE f32->bf16
    unsigned int u = __builtin_bit_cast(unsigned int, f);
    u += 0x7FFF + ((u >> 16) & 1);
    return (ushort)(u >> 16);
}
__device__ __forceinline__ float bf2f(ushort u) {
    return __builtin_bit_cast(float, ((unsigned int)u) << 16);
}
__device__ __forceinline__ unsigned int pk2(float lo, float hi) {
    return (unsigned int)f2bf(lo) | ((unsigned int)f2bf(hi) << 16);
}

// ---------------- x -> bf16 ----------------
__global__ __launch_bounds__(256)
void k_x2bf(const float* __restrict__ x, ushort* __restrict__ xb)
{
    const size_t i8 = (size_t)blockIdx.x * 256 + threadIdx.x;   // grid 1024
    float4 v0 = *(const float4*)(x + i8 * 8);
    float4 v1 = *(const float4*)(x + i8 * 8 + 4);
    uint4 o;
    o.x = pk2(v0.x, v0.y); o.y = pk2(v0.z, v0.w);
    o.z = pk2(v1.x, v1.y); o.w = pk2(v1.z, v1.w);
    *(uint4*)(xb + i8 * 8) = o;
}

// ---------------- weight transpose+convert: W f32 [K][N] -> WT bf16 [N][K] ----
__global__ __launch_bounds__(256)
void k_wT(const float* __restrict__ s0, const float* __restrict__ s1,
          const float* __restrict__ s2, const float* __restrict__ s3,
          ushort* __restrict__ dst)
{
    const int z = blockIdx.z;
    const float* W = (z == 0) ? s0 : (z == 1) ? s1 : (z == 2) ? s2 : s3;
    ushort* WT = dst + (size_t)z * (1024 * 1024);
    __shared__ float t[64][65];
    const int n0 = blockIdx.x * 64, k0 = blockIdx.y * 64;
    const int rr = threadIdx.x >> 4, cc = threadIdx.x & 15;
#pragma unroll
    for (int i = 0; i < 4; ++i) {
        const int row = i * 16 + rr;
        float4 v = *(const float4*)(W + (size_t)(k0 + row) * 1024 + n0 + cc * 4);
        t[row][cc * 4 + 0] = v.x; t[row][cc * 4 + 1] = v.y;
        t[row][cc * 4 + 2] = v.z; t[row][cc * 4 + 3] = v.w;
    }
    __syncthreads();
#pragma unroll
    for (int i = 0; i < 4; ++i) {
        const int n = i * 16 + rr;
        const int kc = cc * 4;
        ushort4 o;
        o.x = f2bf(t[kc + 0][n]); o.y = f2bf(t[kc + 1][n]);
        o.z = f2bf(t[kc + 2][n]); o.w = f2bf(t[kc + 3][n]);
        *(ushort4*)(WT + (size_t)(n0 + n) * 1024 + k0 + kc) = o;
    }
}

// ------------- bf16 MFMA GEMM: C = A(bf16 [M][K]) x BT(bf16 [N][K]) -------------
#define LDSB 40
__device__ __forceinline__ void gemm_tile_mfma(const ushort* __restrict__ A,
                                               const ushort* __restrict__ BT,
                                               float* __restrict__ C,
                                               int brow, int bcol)
{
    __shared__ ushort As[128 * LDSB];
    __shared__ ushort Bs[128 * LDSB];
    const int tid  = threadIdx.x;
    const int lane = tid & 63;
    const int wv   = tid >> 6;
    const int wm   = (wv >> 1) * 64;
    const int wn   = (wv & 1) * 64;
    const int l15  = lane & 15;
    const int k8   = (lane >> 4) * 8;
    const int srow = tid >> 1;
    const int skh  = (tid & 1) * 16;

    f32x4 acc[4][4];
#pragma unroll
    for (int i = 0; i < 4; ++i)
#pragma unroll
        for (int j = 0; j < 4; ++j)
#pragma unroll
            for (int e = 0; e < 4; ++e) acc[i][j][e] = 0.f;

    const ushort* arow = A  + (size_t)(brow + srow) * 1024 + skh;
    const ushort* brp  = BT + (size_t)(bcol + srow) * 1024 + skh;
    ushort* asw = As + srow * LDSB + skh;
    ushort* bsw = Bs + srow * LDSB + skh;

    for (int k0 = 0; k0 < 1024; k0 += 32) {
        uint4 a0 = *(const uint4*)(arow + k0);
        uint4 a1 = *(const uint4*)(arow + k0 + 8);
        uint4 b0 = *(const uint4*)(brp + k0);
        uint4 b1 = *(const uint4*)(brp + k0 + 8);
        __syncthreads();
        *(uint4*)(asw)     = a0;
        *(uint4*)(asw + 8) = a1;
        *(uint4*)(bsw)     = b0;
        *(uint4*)(bsw + 8) = b1;
        __syncthreads();
        short8 af[4], bf[4];
#pragma unroll
        for (int i = 0; i < 4; ++i)
            af[i] = *(const short8*)(As + (wm + i * 16 + l15) * LDSB + k8);
#pragma unroll
        for (int j = 0; j < 4; ++j)
            bf[j] = *(const short8*)(Bs + (wn + j * 16 + l15) * LDSB + k8);
#pragma unroll
        for (int i = 0; i < 4; ++i)
#pragma unroll
            for (int j = 0; j < 4; ++j)
                acc[i][j] = MFMA(af[i], bf[j], acc[i][j], 0, 0, 0);
    }
    const int l4 = lane >> 4;
#pragma unroll
    for (int i = 0; i < 4; ++i)
#pragma unroll
        for (int j = 0; j < 4; ++j)
#pragma unroll
            for (int r = 0; r < 4; ++r)
                C[(size_t)(brow + wm + i * 16 + l4 * 4 + r) * 1024 +
                  bcol + wn + j * 16 + l15] = acc[i][j][r];
}

__global__ __launch_bounds__(256)
void k_gemm4(const ushort* __restrict__ A, const ushort* __restrict__ WT,
             float* __restrict__ Cbase)
{
    const ushort* BT = WT + (size_t)blockIdx.z * (1024 * 1024);
    float* C = Cbase + (size_t)blockIdx.z * SZf;
    gemm_tile_mfma(A, BT, C, blockIdx.y * 128, blockIdx.x * 128);
}

__global__ __launch_bounds__(256)
void k_gemm1(const ushort* __restrict__ A, const ushort* __restrict__ BT,
             float* __restrict__ C)
{
    gemm_tile_mfma(A, BT, C, blockIdx.y * 128, blockIdx.x * 128);
}

// -------- alpha/beta small GEMM + sigmoid; writes TRANSPOSED [bh][t] --------
__global__ __launch_bounds__(64)
void k_ab(const float* __restrict__ x, const float* __restrict__ Wa,
          const float* __restrict__ ba, const float* __restrict__ Wb,
          const float* __restrict__ bb, float* __restrict__ aT,
          float* __restrict__ bT)
{
    const int r = blockIdx.x;
    const int lane = threadIdx.x;
    const int b = r >> 10, t = r & 1023;
    const float* xr = x + (size_t)r * HID_;
    float acc[16];
#pragma unroll
    for (int n = 0; n < 16; ++n) acc[n] = 0.f;
    for (int c = lane; c < HID_; c += 64) {
        const float xv = xr[c];
        const float* wa = Wa + c * 8;
        const float* wb = Wb + c * 8;
#pragma unroll
        for (int n = 0; n < 8; ++n) {
            acc[n]     = fmaf(xv, wa[n], acc[n]);
            acc[8 + n] = fmaf(xv, wb[n], acc[8 + n]);
        }
    }
#pragma unroll
    for (int n = 0; n < 16; ++n) {
#pragma unroll
        for (int m = 32; m; m >>= 1) acc[n] += __shfl_xor(acc[n], m);
    }
    if (lane < 8) {
        aT[(size_t)(b * 8 + lane) * TSEQ + t] = sig_(acc[lane] + ba[lane]);
        bT[(size_t)(b * 8 + lane) * TSEQ + t] = sig_(acc[8 + lane] + bb[lane]);
    }
}

// -------- causal depthwise conv K=4 + SiLU (+scale), in-place, T-parallel ----
__global__ __launch_bounds__(256)
void k_conv_save(const float* __restrict__ q, const float* __restrict__ k,
                 const float* __restrict__ v, float* __restrict__ scr)
{
    const int z = blockIdx.z, b = blockIdx.y, j = blockIdx.x + 1;
    const float* y = (z == 0) ? q : (z == 1) ? k : v;
    float* d = scr + ((size_t)(z * 2 + b) * 15 + (j - 1)) * 3 * 1024;
    const float* s = y + ((size_t)b * TSEQ + j * 64 - 3) * HID_;
    for (int i = threadIdx.x; i < 3 * 1024; i += 256)
        d[i] = s[i];
}

__global__ __launch_bounds__(256)
void k_conv_apply(float* __restrict__ q, float* __restrict__ k, float* __restrict__ v,
                  const float* __restrict__ scr,
                  const float* __restrict__ wq, const float* __restrict__ bq,
                  const float* __restrict__ wk, const float* __restrict__ bk,
                  const float* __restrict__ wv, const float* __restrict__ bv)
{
    const int z = blockIdx.z, b = blockIdx.y;
    const int j = blockIdx.x >> 2, cg = blockIdx.x & 3;
    float* y          = (z == 0) ? q  : (z == 1) ? k  : v;
    const float* w    = (z == 0) ? wq : (z == 1) ? wk : wv;
    const float* bias = (z == 0) ? bq : (z == 1) ? bk : bv;
    const float scale = (z == 1) ? 0.08838834764831845f : 1.f;
    const int c = cg * 256 + threadIdx.x;
    const float w0 = w[c * 4], w1 = w[c * 4 + 1], w2 = w[c * 4 + 2], w3 = w[c * 4 + 3];
    const float bs = bias[c];
    float y0 = 0.f, y1 = 0.f, y2 = 0.f;
    if (j > 0) {
        const float* s = scr + ((size_t)(z * 2 + b) * 15 + (j - 1)) * 3 * 1024 + c;
        y0 = s[0]; y1 = s[1024]; y2 = s[2048];
    }
    float* yp = y + ((size_t)b * TSEQ + j * 64) * HID_ + c;
#pragma unroll 4
    for (int t = 0; t < 64; ++t) {
        float y3  = yp[(size_t)t * HID_];
        float acc = fmaf(w0, y0, fmaf(w1, y1, fmaf(w2, y2, fmaf(w3, y3, bs))));
        float sv  = acc * sig_(acc) * scale;
        yp[(size_t)t * HID_] = sv;
        y0 = y1; y1 = y2; y2 = y3;
    }
}

// ---------- k_stage: pre-format K,Q bf16 (chunk layout) + V bf16 [dv][t] -----
__global__ __launch_bounds__(256)
void k_stage(const float* __restrict__ klin, const float* __restrict__ qlin,
             const float* __restrict__ vlin,
             ushort* __restrict__ Kst, ushort* __restrict__ Qst,
             ushort* __restrict__ Vst)
{
    const int cid = blockIdx.x;          // bh*16 + c
    const int bh = cid >> 4, c = cid & 15;
    const int b = bh >> 3, h = bh & 7;
    const int tid = threadIdx.x;
    const int t0 = c * LCH;
    __shared__ ushort Vl[128 * 72];
    const float* kb = klin + ((size_t)b * TSEQ + t0) * HID_ + h * DK;
    const float* qb = qlin + ((size_t)b * TSEQ + t0) * HID_ + h * DK;
    const float* vb = vlin + ((size_t)b * TSEQ + t0) * HID_ + h * DV;
    const size_t go = (size_t)cid * 8192;
#pragma unroll
    for (int j = 0; j < 8; ++j) {
        const int i4 = tid + j * 256;
        const int row = i4 >> 5, c4 = i4 & 31;
        float4 kv = *(const float4*)(kb + (size_t)row * HID_ + c4 * 4);
        float4 qv = *(const float4*)(qb + (size_t)row * HID_ + c4 * 4);
        float4 vv = *(const float4*)(vb + (size_t)row * HID_ + c4 * 4);
        uint2 kp; kp.x = pk2(kv.x, kv.y); kp.y = pk2(kv.z, kv.w);
        uint2 qp; qp.x = pk2(qv.x, qv.y); qp.y = pk2(qv.z, qv.w);
        *(uint2*)(Kst + go + row * 128 + c4 * 4) = kp;
        *(uint2*)(Qst + go + row * 128 + c4 * 4) = qp;
        const int dv0 = c4 * 4;
        Vl[(dv0 + 0) * 72 + row] = f2bf(vv.x);
        Vl[(dv0 + 1) * 72 + row] = f2bf(vv.y);
        Vl[(dv0 + 2) * 72 + row] = f2bf(vv.z);
        Vl[(dv0 + 3) * 72 + row] = f2bf(vv.w);
    }
    __syncthreads();
#pragma unroll
    for (int j = 0; j < 4; ++j) {                 // V [dv][t] bf16
        const int idx = tid + j * 256;
        const int dv = idx >> 3, tq = (idx & 7) * 8;
        *(uint4*)(Vst + go + dv * 64 + tq) = *(const uint4*)(Vl + dv * 72 + tq);
    }
}

// ============ kernel P: per-chunk parallel precompute (M, G, decays) =========
__global__ __launch_bounds__(256)
void k_prep(const ushort* __restrict__ Kst, const ushort* __restrict__ Qst,
            const float* __restrict__ aT, const float* __restrict__ bT,
            ushort* __restrict__ Mg, ushort* __restrict__ Gg,
            float* __restrict__ pug, float* __restrict__ pog,
            float* __restrict__ cg, float* __restrict__ dtotg)
{
    const int cid = blockIdx.x;
    const int bh = cid >> 4, c = cid & 15;
    const int tid = threadIdx.x;
    const int t0 = c * LCH;

    __shared__ ushort Kb[64 * KSTR], Qb[64 * KSTR];
    __shared__ float Ef[64 * ESTR];
    __shared__ float Mf[64 * ESTR];
    __shared__ float cums[64], bv[64];

    if (tid < 64) {
        const float a = aT[(size_t)bh * TSEQ + t0 + tid];
        bv[tid] = bT[(size_t)bh * TSEQ + t0 + tid];
        float cs = __logf(a);
#pragma unroll
        for (int d = 1; d < 64; d <<= 1) {
            float pv = __shfl_up(cs, d);
            if (tid >= d) cs += pv;
        }
        cums[tid] = cs;
    }
    const size_t go = (size_t)cid * 8192;
#pragma unroll
    for (int j = 0; j < 4; ++j) {
        const int i16 = tid + j * 256;
        const int row = i16 >> 4, col = (i16 & 15) * 8;
        *(uint4*)(Kb + row * KSTR + col) = *(const uint4*)(Kst + go + i16 * 8);
        *(uint4*)(Qb + row * KSTR + col) = *(const uint4*)(Qst + go + i16 * 8);
    }
    __syncthreads();

    const int wv = tid >> 6, l = tid & 63, l15 = l & 15, lq = l >> 4;
    const int k8o = lq * 8;
    f32x4 accK[4], accQ4[4];
#pragma unroll
    for (int j = 0; j < 4; ++j) {
        accK[j] = f32x4{0.f, 0.f, 0.f, 0.f};
        accQ4[j] = f32x4{0.f, 0.f, 0.f, 0.f};
    }
#pragma unroll
    for (int kk = 0; kk < 4; ++kk) {
        short8 aK = *(const short8*)(Kb + (wv * 16 + l15) * KSTR + kk * 32 + k8o);
        short8 aQ = *(const short8*)(Qb + (wv * 16 + l15) * KSTR + kk * 32 + k8o);
#pragma unroll
        for (int js = 0; js < 4; ++js) {
            short8 bK = *(const short8*)(Kb + (js * 16 + l15) * KSTR + kk * 32 + k8o);
            accK[js]  = MFMA(aK, bK, accK[js], 0, 0, 0);
            accQ4[js] = MFMA(aQ, bK, accQ4[js], 0, 0, 0);
        }
    }
    ushort* Gc = Gg + (size_t)cid * 4096;
#pragma unroll
    for (int js = 0; js < 4; ++js) {
#pragma unroll
        for (int r = 0; r < 4; ++r) {
            const int t = wv * 16 + lq * 4 + r;
            const int s = js * 16 + l15;
            const float cp = (t > 0) ? cums[t - 1] : 0.f;
            Ef[t * ESTR + s] = (s < t) ? __expf(cp - cums[s]) * accK[js][r] : 0.f;
            const float gv = (s <= t) ? __expf(cums[t] - cums[s]) * accQ4[js][r] : 0.f;
            Gc[t * 64 + s] = f2bf(gv);
        }
    }
    __syncthreads();

    if (tid < 64) {                     // M-solve: lane s owns column s
        const int s = tid;
        for (int r = 0; r < 64; ++r) Mf[r * ESTR + s] = 0.f;
        Mf[s * ESTR + s] = bv[s];
        for (int t = 1; t < 64; ++t) {
            float s0 = 0.f, s1 = 0.f;
            int r = 0;
            for (; r + 1 < t; r += 2) {
                s0 = fmaf(Ef[t * ESTR + r],     Mf[r * ESTR + s],       s0);
                s1 = fmaf(Ef[t * ESTR + r + 1], Mf[(r + 1) * ESTR + s], s1);
            }
            if (r < t) s0 = fmaf(Ef[t * ESTR + r], Mf[r * ESTR + s], s0);
            if (s < t) Mf[t * ESTR + s] = -bv[t] * (s0 + s1);
        }
    }
    __syncthreads();
    ushort* Mc = Mg + (size_t)cid * 4096;
#pragma unroll
    for (int j = 0; j < 16; ++j) {
        const int e = tid + j * 256;
        Mc[e] = f2bf(Mf[(e >> 6) * ESTR + (e & 63)]);
    }
    if (tid < 64) {
        const float cp = (tid > 0) ? cums[tid - 1] : 0.f;
        pug[cid * 64 + tid] = __expf(cp);
        pog[cid * 64 + tid] = __expf(cums[tid]);
        cg [cid * 64 + tid] = __expf(cums[63] - cums[tid]);
        if (tid == 0) dtotg[cid] = __expf(cums[63]);
    }
}

// ===== kernel S (serial): state recurrence only; outputs S_c, W_c per chunk ==
// 64 blocks = bh x 4 dv-slices of 32; 4 waves (R8 structure). Per chunk loads
// only K(16K) + M(8K) + V(4K bf16); KT built in-LDS; S/W dumped for k_out.
__global__ __launch_bounds__(256)
void k_scan2(const ushort* __restrict__ Kst, const ushort* __restrict__ Vst,
             const ushort* __restrict__ Mg,
             const float* __restrict__ pug, const float* __restrict__ cgd,
             const float* __restrict__ dtg,
             ushort* __restrict__ Sst, ushort* __restrict__ Wst)
{
    const int blk = blockIdx.x;          // bh*4 + rb
    const int bh = blk >> 2, rb = blk & 3;
    const int tid = threadIdx.x;
    const int wv = tid >> 6, l = tid & 63, l15 = l & 15, lq = l >> 4;
    const int k8o = lq * 8;
    const int trow  = wv >> 1;
    const int tcol0 = (wv & 1) * 2;
    const int scol0 = (wv & 1) * 4;

    __shared__ ushort Kb[64 * KSTR];
    __shared__ ushort KTb[128 * 72];
    __shared__ ushort Mb[64 * 72];
    __shared__ ushort Vb[32 * 72];
    __shared__ ushort Shb[32 * KSTR], Slb[32 * KSTR];
    __shared__ ushort Yb[32 * 72], Wb[32 * 72], Wcb[32 * 72];
    __shared__ float  puv[64], cv2[64], dts[1];

    f32x4 accS[4];
#pragma unroll
    for (int m = 0; m < 4; ++m) accS[m] = f32x4{0.f, 0.f, 0.f, 0.f};

    uint4 rk[4], rm[2], rv;
    float rpu = 0.f, rcv = 0.f, rdt = 0.f;

    auto LOADC = [&](int cc) {
        const int cid = bh * 16 + cc;
        const size_t go = (size_t)cid * 8192;
#pragma unroll
        for (int j = 0; j < 4; ++j)
            rk[j] = *(const uint4*)(Kst + go + (tid + j * 256) * 8);
#pragma unroll
        for (int j = 0; j < 2; ++j)
            rm[j] = *(const uint4*)(Mg + (size_t)cid * 4096 + (tid + j * 256) * 8);
        rv = *(const uint4*)(Vst + go + rb * 2048 + tid * 8);
        if (tid < 64) {
            rpu = pug[cid * 64 + tid];
            rcv = cgd[cid * 64 + tid];
            if (tid == 0) rdt = dtg[cid];
        }
    };
    auto WRITEC = [&]() {
#pragma unroll
        for (int j = 0; j < 4; ++j) {
            const int i16 = tid + j * 256;
            *(uint4*)(Kb + (i16 >> 4) * KSTR + (i16 & 15) * 8) = rk[j];
        }
#pragma unroll
        for (int j = 0; j < 2; ++j) {
            const int i8 = tid + j * 256;
            *(uint4*)(Mb + (i8 >> 3) * 72 + (i8 & 7) * 8) = rm[j];
        }
        *(uint4*)(Vb + (tid >> 3) * 72 + (tid & 7) * 8) = rv;
        if (tid < 64) {
            puv[tid] = rpu; cv2[tid] = rcv;
            if (tid == 0) dts[0] = rdt;
        }
    };

    LOADC(0); WRITEC();
    __syncthreads();

    for (int c = 0; c < NCK; ++c) {
        if (c + 1 < NCK) LOADC(c + 1);          // in flight through compute
        // ---- KT-build: KTb[dk][t] from Kb[t][dk] (bank-staggered b16 writes)
#pragma unroll
        for (int j = 0; j < 4; ++j) {
            const int i16 = tid + j * 256;
            const int t = i16 >> 4, dk0 = (i16 & 15) * 8;
            uint4 v = *(const uint4*)(Kb + t * KSTR + dk0);
            ushort tmp[8]; *(uint4*)tmp = v;
#pragma unroll
            for (int e = 0; e < 8; ++e) {
                const int ep = (e + (l & 7)) & 7;
                KTb[(dk0 + ep) * 72 + t] = tmp[ep];
            }
        }
        // ---- B: state -> LDS hi/lo bf16 (chunk-start state)
#pragma unroll
        for (int m = 0; m < 4; ++m) {
#pragma unroll
            for (int r = 0; r < 4; ++r) {
                const int dv = trow * 16 + lq * 4 + r;
                const int dk = (scol0 + m) * 16 + l15;
                const float sv = accS[m][r];
                const ushort hi = f2bf(sv);
                const float hf = __builtin_bit_cast(float, ((unsigned)hi) << 16);
                Shb[dv * KSTR + dk] = hi;
                Slb[dv * KSTR + dk] = f2bf(sv - hf);
            }
        }
        __syncthreads();
        const float dt = dts[0];                // hoist before WRITEC phase
        // ---- C: U = S.K^T (compensated)
        f32x4 accU[2];
#pragma unroll
        for (int jj = 0; jj < 2; ++jj) accU[jj] = f32x4{0.f, 0.f, 0.f, 0.f};
#pragma unroll
        for (int kk = 0; kk < 4; ++kk) {
            short8 ah = *(const short8*)(Shb + (trow * 16 + l15) * KSTR + kk * 32 + k8o);
            short8 al = *(const short8*)(Slb + (trow * 16 + l15) * KSTR + kk * 32 + k8o);
#pragma unroll
            for (int jj = 0; jj < 2; ++jj) {
                short8 bk = *(const short8*)(Kb + ((tcol0 + jj) * 16 + l15) * KSTR + kk * 32 + k8o);
                accU[jj] = MFMA(ah, bk, accU[jj], 0, 0, 0);
                accU[jj] = MFMA(al, bk, accU[jj], 0, 0, 0);
            }
        }
        // ---- D: Y = V - pu (.) U
#pragma unroll
        for (int jj = 0; jj < 2; ++jj) {
            const int t = (tcol0 + jj) * 16 + l15;
            const float pu = puv[t];
#pragma unroll
            for (int r = 0; r < 4; ++r) {
                const int dv = trow * 16 + lq * 4 + r;
                const float vf = bf2f(Vb[dv * 72 + t]);
                Yb[dv * 72 + t] = f2bf(vf - pu * accU[jj][r]);
            }
        }
        __syncthreads();
        // ---- E: W = Y x M
        f32x4 accW[2];
#pragma unroll
        for (int jj = 0; jj < 2; ++jj) accW[jj] = f32x4{0.f, 0.f, 0.f, 0.f};
#pragma unroll
        for (int kk = 0; kk < 2; ++kk) {
            short8 ay = *(const short8*)(Yb + (trow * 16 + l15) * 72 + kk * 32 + k8o);
#pragma unroll
            for (int jj = 0; jj < 2; ++jj) {
                short8 bm = *(const short8*)(Mb + ((tcol0 + jj) * 16 + l15) * 72 + kk * 32 + k8o);
                accW[jj] = MFMA(ay, bm, accW[jj], 0, 0, 0);
            }
        }
#pragma unroll
        for (int jj = 0; jj < 2; ++jj) {
            const int t = (tcol0 + jj) * 16 + l15;
            const float cvt = cv2[t];
#pragma unroll
            for (int r = 0; r < 4; ++r) {
                const int dv = trow * 16 + lq * 4 + r;
                const float wvl = accW[jj][r];
                Wb[dv * 72 + t]  = f2bf(wvl);
                Wcb[dv * 72 + t] = f2bf(wvl * cvt);
            }
        }
        __syncthreads();
        // ---- G: S = dtot*S + Wc x K  (+ dumps + land next chunk)
#pragma unroll
        for (int m = 0; m < 4; ++m)
#pragma unroll
            for (int r = 0; r < 4; ++r) accS[m][r] *= dt;
#pragma unroll
        for (int kk = 0; kk < 2; ++kk) {
            short8 aw = *(const short8*)(Wcb + (trow * 16 + l15) * 72 + kk * 32 + k8o);
#pragma unroll
            for (int m = 0; m < 4; ++m) {
                short8 bk = *(const short8*)(KTb + ((scol0 + m) * 16 + l15) * 72 + kk * 32 + k8o);
                accS[m] = MFMA(aw, bk, accS[m], 0, 0, 0);
            }
        }
        {   // S-dump (chunk-start state, hi bf16) + W-dump
            const int cid = bh * 16 + c;
            const size_t so = (size_t)cid * 16384 + rb * 4096;
#pragma unroll
            for (int j = 0; j < 2; ++j) {
                const int idx = tid + j * 256;
                const int dvl = idx >> 4, ko = (idx & 15) * 8;
                *(uint4*)(Sst + so + dvl * 128 + ko) =
                    *(const uint4*)(Shb + dvl * KSTR + ko);
            }
            *(uint4*)(Wst + (size_t)cid * 8192 + rb * 2048 + (tid >> 3) * 64 + (tid & 7) * 8)
                = *(const uint4*)(Wb + (tid >> 3) * 72 + (tid & 7) * 8);
        }
        if (c + 1 < NCK) WRITEC();
        __syncthreads();
    }
}

// ===== kernel O (parallel): O = po (.) S.Q^T + G.W, fused LayerNorm + gate ====
// 256 blocks = (bh, chunk); 4 waves; writes ogb bf16 directly.
__global__ __launch_bounds__(256)
void k_out(const ushort* __restrict__ Sst, const ushort* __restrict__ Qst,
           const ushort* __restrict__ Gg, const ushort* __restrict__ Wst,
           const float* __restrict__ pog, const float* __restrict__ g_lin,
           const float* __restrict__ lng, const float* __restrict__ lnb,
           ushort* __restrict__ ogb)
{
    const int cid = blockIdx.x;
    const int bh = cid >> 4, c = cid & 15;
    const int b = bh >> 3, h = bh & 7;
    const int t0 = c * LCH;
    const int tid = threadIdx.x;
    const int wv = tid >> 6, l = tid & 63, l15 = l & 15, lq = l >> 4;
    const int k8o = lq * 8;

    __shared__ ushort Sb[128 * KSTR];
    __shared__ ushort Qb[64 * KSTR];
    __shared__ ushort Gb[64 * 72];
    __shared__ ushort Wqb[128 * 72];
    __shared__ float  Ot[64 * 132];
    __shared__ float  pov[64];

#pragma unroll
    for (int j = 0; j < 8; ++j) {
        const int i16 = tid + j * 256;
        *(uint4*)(Sb + (i16 >> 4) * KSTR + (i16 & 15) * 8) =
            *(const uint4*)(Sst + (size_t)cid * 16384 + i16 * 8);
    }
#pragma unroll
    for (int j = 0; j < 4; ++j) {
        const int i16 = tid + j * 256;
        *(uint4*)(Qb + (i16 >> 4) * KSTR + (i16 & 15) * 8) =
            *(const uint4*)(Qst + (size_t)cid * 8192 + i16 * 8);
        const int i8 = i16;
        *(uint4*)(Wqb + (i8 >> 3) * 72 + (i8 & 7) * 8) =
            *(const uint4*)(Wst + (size_t)cid * 8192 + i8 * 8);
    }
#pragma unroll
    for (int j = 0; j < 2; ++j) {
        const int i8 = tid + j * 256;
        *(uint4*)(Gb + (i8 >> 3) * 72 + (i8 & 7) * 8) =
            *(const uint4*)(Gg + (size_t)cid * 4096 + i8 * 8);
    }
    if (tid < 64) pov[tid] = pog[cid * 64 + tid];
    __syncthreads();

    // compute: wave wv owns dv rows wv*32..wv*32+31 (2 MFMA row-tiles)
#pragma unroll
    for (int i = 0; i < 2; ++i) {
        const int dvt = wv * 2 + i;
        f32x4 acc[4], acg[4];
#pragma unroll
        for (int jj = 0; jj < 4; ++jj) {
            acc[jj] = f32x4{0.f, 0.f, 0.f, 0.f};
            acg[jj] = f32x4{0.f, 0.f, 0.f, 0.f};
        }
#pragma unroll
        for (int kk = 0; kk < 4; ++kk) {
            short8 sa = *(const short8*)(Sb + (dvt * 16 + l15) * KSTR + kk * 32 + k8o);
#pragma unroll
            for (int jj = 0; jj < 4; ++jj) {
                short8 qb = *(const short8*)(Qb + (jj * 16 + l15) * KSTR + kk * 32 + k8o);
                acc[jj] = MFMA(sa, qb, acc[jj], 0, 0, 0);
            }
        }
#pragma unroll
        for (int kk = 0; kk < 2; ++kk) {
            short8 wa = *(const short8*)(Wqb + (dvt * 16 + l15) * 72 + kk * 32 + k8o);
#pragma unroll
            for (int jj = 0; jj < 4; ++jj) {
                short8 gb = *(const short8*)(Gb + (jj * 16 + l15) * 72 + kk * 32 + k8o);
                acg[jj] = MFMA(wa, gb, acg[jj], 0, 0, 0);
            }
        }
#pragma unroll
        for (int jj = 0; jj < 4; ++jj) {
            const int t = jj * 16 + l15;
            const float po = pov[t];
            float4 o4;
            o4.x = po * acc[jj][0] + acg[jj][0];
            o4.y = po * acc[jj][1] + acg[jj][1];
            o4.z = po * acc[jj][2] + acg[jj][2];
            o4.w = po * acc[jj][3] + acg[jj][3];
            *(float4*)(Ot + t * 132 + dvt * 16 + lq * 4) = o4;
        }
    }
    __syncthreads();

    // fused LayerNorm(128) + sigmoid gate, 16 t-rows per wave
    const int d = l * 2;
    const float lg0 = lng[d], lg1 = lng[d + 1];
    const float lb0 = lnb[d], lb1 = lnb[d + 1];
    const size_t btbase = (size_t)b * TSEQ + t0 + wv * 16;
#pragma unroll 1
    for (int rr = 0; rr < 16; ++rr) {
        const int t = wv * 16 + rr;
        float2 xv = *(const float2*)(Ot + t * 132 + d);
        float s = xv.x + xv.y;
#pragma unroll
        for (int m = 32; m; m >>= 1) s += __shfl_xor(s, m);
        const float mu = s * (1.f / 128.f);
        const float d0 = xv.x - mu, d1 = xv.y - mu;
        float v = d0 * d0 + d1 * d1;
#pragma unroll
        for (int m = 32; m; m >>= 1) v += __shfl_xor(v, m);
        const float inv = rsqrtf(v * (1.f / 128.f) + 1e-5f);
        const float* gp = g_lin + (btbase + rr) * HID_ + h * DV;
        const float g0 = sig_(gp[d]), g1 = sig_(gp[d + 1]);
        const float y0 = (d0 * inv * lg0 + lb0) * g0;
        const float y1 = (d1 * inv * lg1 + lb1) * g1;
        *(uint*)(ogb + (btbase + rr) * HID_ + h * DV + d) = pk2(y0, y1);
    }
}

extern "C" void kernel_launch(void* const* d_in, const int* in_sizes, int n_in,
                              void* d_out, int out_size, void* d_ws, size_t ws_size,
                              hipStream_t stream)
{
    const float* x   = (const float*)d_in[0];
    const float* Wq  = (const float*)d_in[1];
    const float* Wk  = (const float*)d_in[2];
    const float* Wv  = (const float*)d_in[3];
    const float* cqw = (const float*)d_in[4];
    const float* cqb = (const float*)d_in[5];
    const float* ckw = (const float*)d_in[6];
    const float* ckb = (const float*)d_in[7];
    const float* cvw = (const float*)d_in[8];
    const float* cvb = (const float*)d_in[9];
    const float* Wa  = (const float*)d_in[10];
    const float* ba  = (const float*)d_in[11];
    const float* Wb  = (const float*)d_in[12];
    const float* bb  = (const float*)d_in[13];
    const float* Wg  = (const float*)d_in[14];
    const float* Wo  = (const float*)d_in[15];
    const float* lng = (const float*)d_in[16];
    const float* lnb = (const float*)d_in[17];
    float* out = (float*)d_out;
    float* ws  = (float*)d_ws;

    float* q_lin = ws;                       // f32; dead after k_stage; ogb reuses
    float* k_lin = ws + 1 * (size_t)SZf;     // f32; dead after k_stage; WoT reuses
    float* v_lin = ws + 2 * (size_t)SZf;     // f32; dead after k_stage
    float* g_lin = ws + 3 * (size_t)SZf;     // read by k_out
    float* o_buf = ws + 4 * (size_t)SZf;     // WT4 -> conv scratch -> Sst
    float* aT    = ws + 5 * (size_t)SZf;
    float* bT    = aT + 16 * TSEQ;
    float* pug   = bT + 16 * TSEQ;
    float* pog   = pug + 256 * 64;
    float* cgd   = pog + 256 * 64;
    float* dtg   = cgd + 256 * 64;

    float*  tail = ws + 5 * (size_t)SZf + 131072;
    ushort* Kst  = (ushort*)tail;                    // 4MB
    ushort* Qst  = Kst + (size_t)256 * 8192;         // 4MB
    ushort* xbf  = Qst + (size_t)256 * 8192;         // 4MB; dead after gemm4
    ushort* Vst  = xbf;                              // reuse: written by k_stage

    ushort* WT4 = (ushort*)o_buf;            // dead after gemm4
    ushort* WoT = (ushort*)k_lin;            // written after k_stage
    ushort* ogb = (ushort*)q_lin;            // bf16 LN output (4MB)
    ushort* Sst = (ushort*)o_buf;            // 8MB: 256 x [128][128] bf16
    ushort* Mg  = (ushort*)out;              // 2MB
    ushort* Gg  = Mg + (size_t)256 * 4096;   // 2MB
    ushort* Wst = Gg + (size_t)256 * 4096;   // 4MB -> fills d_out exactly

    k_x2bf<<<1024, 256, 0, stream>>>(x, xbf);
    k_wT<<<dim3(16, 16, 4), 256, 0, stream>>>(Wq, Wk, Wv, Wg, WT4);
    k_gemm4<<<dim3(8, 16, 4), 256, 0, stream>>>(xbf, WT4, ws);
    k_ab<<<ROWS, 64, 0, stream>>>(x, Wa, ba, Wb, bb, aT, bT);
    k_conv_save<<<dim3(15, 2, 3), 256, 0, stream>>>(q_lin, k_lin, v_lin, o_buf);
    k_conv_apply<<<dim3(64, 2, 3), 256, 0, stream>>>(q_lin, k_lin, v_lin, o_buf,
                                                     cqw, cqb, ckw, ckb, cvw, cvb);
    k_stage<<<256, 256, 0, stream>>>(k_lin, q_lin, v_lin, Kst, Qst, Vst);
    k_prep<<<256, 256, 0, stream>>>(Kst, Qst, aT, bT, Mg, Gg, pug, pog, cgd, dtg);
    k_wT<<<dim3(16, 16, 1), 256, 0, stream>>>(Wo, Wo, Wo, Wo, WoT);
    k_scan2<<<64, 256, 0, stream>>>(Kst, Vst, Mg, pug, cgd, dtg, Sst, Wst);
    k_out<<<256, 256, 0, stream>>>(Sst, Qst, Gg, Wst, pog, g_lin, lng, lnb, ogb);
    k_gemm1<<<dim3(8, 16), 256, 0, stream>>>(ogb, WoT, out);
}

// Round 11
// 231.421 us; speedup vs baseline: 1.4503x; 1.0246x over previous
//
#include <hip/hip_runtime.h>

#define TSEQ 1024
#define HID_ 1024
#define NH 8
#define DK 128
#define DV 128
#define ROWS 2048               // B*T
#define SZf (ROWS * HID_)       // floats per [2048,1024] matrix
#define LCH 64                  // scan chunk length
#define NCK 16                  // chunks per (b,h)
#define KSTR 136                // bf16 LDS stride for [64][128] tiles
#define ESTR 65

typedef __attribute__((ext_vector_type(8))) short short8;
typedef __attribute__((ext_vector_type(4))) float f32x4;
#define MFMA __builtin_amdgcn_mfma_f32_16x16x32_bf16

__device__ __forceinline__ float sig_(float x) { return 1.f / (1.f + __expf(-x)); }

__device__ __forceinline__ ushort f2bf(float f) {   // RNE f32->bf16
    unsigned int u = __builtin_bit_cast(unsigned int, f);
    u += 0x7FFF + ((u >> 16) & 1);
    return (ushort)(u >> 16);
}
__device__ __forceinline__ float bf2f(ushort u) {
    return __builtin_bit_cast(float, ((unsigned int)u) << 16);
}
__device__ __forceinline__ unsigned int pk2(float lo, float hi) {
    return (unsigned int)f2bf(lo) | ((unsigned int)f2bf(hi) << 16);
}

// ---------------- x -> bf16 ----------------
__global__ __launch_bounds__(256)
void k_x2bf(const float* __restrict__ x, ushort* __restrict__ xb)
{
    const size_t i8 = (size_t)blockIdx.x * 256 + threadIdx.x;   // grid 1024
    float4 v0 = *(const float4*)(x + i8 * 8);
    float4 v1 = *(const float4*)(x + i8 * 8 + 4);
    uint4 o;
    o.x = pk2(v0.x, v0.y); o.y = pk2(v0.z, v0.w);
    o.z = pk2(v1.x, v1.y); o.w = pk2(v1.z, v1.w);
    *(uint4*)(xb + i8 * 8) = o;
}

// ---------------- weight transpose+convert: W f32 [K][N] -> WT bf16 [N][K] ----
__global__ __launch_bounds__(256)
void k_wT(const float* __restrict__ s0, const float* __restrict__ s1,
          const float* __restrict__ s2, const float* __restrict__ s3,
          ushort* __restrict__ dst)
{
    const int z = blockIdx.z;
    const float* W = (z == 0) ? s0 : (z == 1) ? s1 : (z == 2) ? s2 : s3;
    ushort* WT = dst + (size_t)z * (1024 * 1024);
    __shared__ float t[64][65];
    const int n0 = blockIdx.x * 64, k0 = blockIdx.y * 64;
    const int rr = threadIdx.x >> 4, cc = threadIdx.x & 15;
#pragma unroll
    for (int i = 0; i < 4; ++i) {
        const int row = i * 16 + rr;
        float4 v = *(const float4*)(W + (size_t)(k0 + row) * 1024 + n0 + cc * 4);
        t[row][cc * 4 + 0] = v.x; t[row][cc * 4 + 1] = v.y;
        t[row][cc * 4 + 2] = v.z; t[row][cc * 4 + 3] = v.w;
    }
    __syncthreads();
#pragma unroll
    for (int i = 0; i < 4; ++i) {
        const int n = i * 16 + rr;
        const int kc = cc * 4;
        ushort4 o;
        o.x = f2bf(t[kc + 0][n]); o.y = f2bf(t[kc + 1][n]);
        o.z = f2bf(t[kc + 2][n]); o.w = f2bf(t[kc + 3][n]);
        *(ushort4*)(WT + (size_t)(n0 + n) * 1024 + k0 + kc) = o;
    }
}

// ------------- bf16 MFMA GEMM: C = A(bf16 [M][K]) x BT(bf16 [N][K]) -------------
#define LDSB 40
__device__ __forceinline__ void gemm_tile_mfma(const ushort* __restrict__ A,
                                               const ushort* __restrict__ BT,
                                               float* __restrict__ C,
                                               int brow, int bcol)
{
    __shared__ ushort As[128 * LDSB];
    __shared__ ushort Bs[128 * LDSB];
    const int tid  = threadIdx.x;
    const int lane = tid & 63;
    const int wv   = tid >> 6;
    const int wm   = (wv >> 1) * 64;
    const int wn   = (wv & 1) * 64;
    const int l15  = lane & 15;
    const int k8   = (lane >> 4) * 8;
    const int srow = tid >> 1;
    const int skh  = (tid & 1) * 16;

    f32x4 acc[4][4];
#pragma unroll
    for (int i = 0; i < 4; ++i)
#pragma unroll
        for (int j = 0; j < 4; ++j)
#pragma unroll
            for (int e = 0; e < 4; ++e) acc[i][j][e] = 0.f;

    const ushort* arow = A  + (size_t)(brow + srow) * 1024 + skh;
    const ushort* brp  = BT + (size_t)(bcol + srow) * 1024 + skh;
    ushort* asw = As + srow * LDSB + skh;
    ushort* bsw = Bs + srow * LDSB + skh;

    for (int k0 = 0; k0 < 1024; k0 += 32) {
        uint4 a0 = *(const uint4*)(arow + k0);
        uint4 a1 = *(const uint4*)(arow + k0 + 8);
        uint4 b0 = *(const uint4*)(brp + k0);
        uint4 b1 = *(const uint4*)(brp + k0 + 8);
        __syncthreads();
        *(uint4*)(asw)     = a0;
        *(uint4*)(asw + 8) = a1;
        *(uint4*)(bsw)     = b0;
        *(uint4*)(bsw + 8) = b1;
        __syncthreads();
        short8 af[4], bf[4];
#pragma unroll
        for (int i = 0; i < 4; ++i)
            af[i] = *(const short8*)(As + (wm + i * 16 + l15) * LDSB + k8);
#pragma unroll
        for (int j = 0; j < 4; ++j)
            bf[j] = *(const short8*)(Bs + (wn + j * 16 + l15) * LDSB + k8);
#pragma unroll
        for (int i = 0; i < 4; ++i)
#pragma unroll
            for (int j = 0; j < 4; ++j)
                acc[i][j] = MFMA(af[i], bf[j], acc[i][j], 0, 0, 0);
    }
    const int l4 = lane >> 4;
#pragma unroll
    for (int i = 0; i < 4; ++i)
#pragma unroll
        for (int j = 0; j < 4; ++j)
#pragma unroll
            for (int r = 0; r < 4; ++r)
                C[(size_t)(brow + wm + i * 16 + l4 * 4 + r) * 1024 +
                  bcol + wn + j * 16 + l15] = acc[i][j][r];
}

__global__ __launch_bounds__(256)
void k_gemm4(const ushort* __restrict__ A, const ushort* __restrict__ WT,
             float* __restrict__ Cbase)
{
    const ushort* BT = WT + (size_t)blockIdx.z * (1024 * 1024);
    float* C = Cbase + (size_t)blockIdx.z * SZf;
    gemm_tile_mfma(A, BT, C, blockIdx.y * 128, blockIdx.x * 128);
}

__global__ __launch_bounds__(256)
void k_gemm1(const ushort* __restrict__ A, const ushort* __restrict__ BT,
             float* __restrict__ C)
{
    gemm_tile_mfma(A, BT, C, blockIdx.y * 128, blockIdx.x * 128);
}

// -------- alpha/beta small GEMM + sigmoid; writes TRANSPOSED [bh][t] --------
__global__ __launch_bounds__(64)
void k_ab(const float* __restrict__ x, const float* __restrict__ Wa,
          const float* __restrict__ ba, const float* __restrict__ Wb,
          const float* __restrict__ bb, float* __restrict__ aT,
          float* __restrict__ bT)
{
    const int r = blockIdx.x;
    const int lane = threadIdx.x;
    const int b = r >> 10, t = r & 1023;
    const float* xr = x + (size_t)r * HID_;
    float acc[16];
#pragma unroll
    for (int n = 0; n < 16; ++n) acc[n] = 0.f;
    for (int c = lane; c < HID_; c += 64) {
        const float xv = xr[c];
        const float* wa = Wa + c * 8;
        const float* wb = Wb + c * 8;
#pragma unroll
        for (int n = 0; n < 8; ++n) {
            acc[n]     = fmaf(xv, wa[n], acc[n]);
            acc[8 + n] = fmaf(xv, wb[n], acc[8 + n]);
        }
    }
#pragma unroll
    for (int n = 0; n < 16; ++n) {
#pragma unroll
        for (int m = 32; m; m >>= 1) acc[n] += __shfl_xor(acc[n], m);
    }
    if (lane < 8) {
        aT[(size_t)(b * 8 + lane) * TSEQ + t] = sig_(acc[lane] + ba[lane]);
        bT[(size_t)(b * 8 + lane) * TSEQ + t] = sig_(acc[8 + lane] + bb[lane]);
    }
}

// -------- causal depthwise conv K=4 + SiLU (+scale), in-place, T-parallel ----
__global__ __launch_bounds__(256)
void k_conv_save(const float* __restrict__ q, const float* __restrict__ k,
                 const float* __restrict__ v, float* __restrict__ scr)
{
    const int z = blockIdx.z, b = blockIdx.y, j = blockIdx.x + 1;
    const float* y = (z == 0) ? q : (z == 1) ? k : v;
    float* d = scr + ((size_t)(z * 2 + b) * 15 + (j - 1)) * 3 * 1024;
    const float* s = y + ((size_t)b * TSEQ + j * 64 - 3) * HID_;
    for (int i = threadIdx.x; i < 3 * 1024; i += 256)
        d[i] = s[i];
}

__global__ __launch_bounds__(256)
void k_conv_apply(float* __restrict__ q, float* __restrict__ k, float* __restrict__ v,
                  const float* __restrict__ scr,
                  const float* __restrict__ wq, const float* __restrict__ bq,
                  const float* __restrict__ wk, const float* __restrict__ bk,
                  const float* __restrict__ wv, const float* __restrict__ bv)
{
    const int z = blockIdx.z, b = blockIdx.y;
    const int j = blockIdx.x >> 2, cg = blockIdx.x & 3;
    float* y          = (z == 0) ? q  : (z == 1) ? k  : v;
    const float* w    = (z == 0) ? wq : (z == 1) ? wk : wv;
    const float* bias = (z == 0) ? bq : (z == 1) ? bk : bv;
    const float scale = (z == 1) ? 0.08838834764831845f : 1.f;
    const int c = cg * 256 + threadIdx.x;
    const float w0 = w[c * 4], w1 = w[c * 4 + 1], w2 = w[c * 4 + 2], w3 = w[c * 4 + 3];
    const float bs = bias[c];
    float y0 = 0.f, y1 = 0.f, y2 = 0.f;
    if (j > 0) {
        const float* s = scr + ((size_t)(z * 2 + b) * 15 + (j - 1)) * 3 * 1024 + c;
        y0 = s[0]; y1 = s[1024]; y2 = s[2048];
    }
    float* yp = y + ((size_t)b * TSEQ + j * 64) * HID_ + c;
#pragma unroll 4
    for (int t = 0; t < 64; ++t) {
        float y3  = yp[(size_t)t * HID_];
        float acc = fmaf(w0, y0, fmaf(w1, y1, fmaf(w2, y2, fmaf(w3, y3, bs))));
        float sv  = acc * sig_(acc) * scale;
        yp[(size_t)t * HID_] = sv;
        y0 = y1; y1 = y2; y2 = y3;
    }
}

// ========== k_stageprep: stage K/Q/V/KT (bf16) + M, G, decays per chunk ======
__global__ __launch_bounds__(256)
void k_stageprep(const float* __restrict__ klin, const float* __restrict__ qlin,
                 const float* __restrict__ vlin,
                 const float* __restrict__ aT, const float* __restrict__ bT,
                 ushort* __restrict__ Kst, ushort* __restrict__ Qst,
                 ushort* __restrict__ Vst, ushort* __restrict__ KTst,
                 ushort* __restrict__ Mg, ushort* __restrict__ Gg,
                 float* __restrict__ pug, float* __restrict__ pog,
                 float* __restrict__ cg, float* __restrict__ dtotg)
{
    const int cid = blockIdx.x;          // bh*16 + c
    const int bh = cid >> 4, c = cid & 15;
    const int b = bh >> 3, h = bh & 7;
    const int tid = threadIdx.x;
    const int t0 = c * LCH;

    __shared__ ushort Kb[64 * KSTR], Qb[64 * KSTR];
    __shared__ ushort Vl[128 * 72];
    __shared__ float Ef[64 * ESTR];
    __shared__ float Mf[64 * ESTR];
    __shared__ float cums[64], bv[64];

    if (tid < 64) {
        const float a = aT[(size_t)bh * TSEQ + t0 + tid];
        bv[tid] = bT[(size_t)bh * TSEQ + t0 + tid];
        float cs = __logf(a);
#pragma unroll
        for (int d = 1; d < 64; d <<= 1) {
            float pv = __shfl_up(cs, d);
            if (tid >= d) cs += pv;
        }
        cums[tid] = cs;
    }
    const float* kb = klin + ((size_t)b * TSEQ + t0) * HID_ + h * DK;
    const float* qb = qlin + ((size_t)b * TSEQ + t0) * HID_ + h * DK;
    const float* vb = vlin + ((size_t)b * TSEQ + t0) * HID_ + h * DV;
    const size_t go = (size_t)cid * 8192;
#pragma unroll
    for (int j = 0; j < 8; ++j) {
        const int i4 = tid + j * 256;
        const int row = i4 >> 5, c4 = i4 & 31;
        float4 kv = *(const float4*)(kb + (size_t)row * HID_ + c4 * 4);
        float4 qv = *(const float4*)(qb + (size_t)row * HID_ + c4 * 4);
        float4 vv = *(const float4*)(vb + (size_t)row * HID_ + c4 * 4);
        uint2 kp; kp.x = pk2(kv.x, kv.y); kp.y = pk2(kv.z, kv.w);
        uint2 qp; qp.x = pk2(qv.x, qv.y); qp.y = pk2(qv.z, qv.w);
        *(uint2*)(Kst + go + row * 128 + c4 * 4) = kp;
        *(uint2*)(Qst + go + row * 128 + c4 * 4) = qp;
        *(uint2*)(Kb + row * KSTR + c4 * 4) = kp;
        *(uint2*)(Qb + row * KSTR + c4 * 4) = qp;
        const int dv0 = c4 * 4;
        Vl[(dv0 + 0) * 72 + row] = f2bf(vv.x);
        Vl[(dv0 + 1) * 72 + row] = f2bf(vv.y);
        Vl[(dv0 + 2) * 72 + row] = f2bf(vv.z);
        Vl[(dv0 + 3) * 72 + row] = f2bf(vv.w);
    }
    __syncthreads();

    // V-dump [dv][t] and KT-dump [dk][t]
#pragma unroll
    for (int j = 0; j < 4; ++j) {
        const int idx = tid + j * 256;
        const int dv = idx >> 3, tq = (idx & 7) * 8;
        *(uint4*)(Vst + go + dv * 64 + tq) = *(const uint4*)(Vl + dv * 72 + tq);
        const int dk = idx >> 3, tt = (idx & 7) * 8;
        ushort tmp[8];
#pragma unroll
        for (int e = 0; e < 8; ++e) tmp[e] = Kb[(tt + e) * KSTR + dk];
        *(uint4*)(KTst + go + dk * 64 + tt) = *(uint4*)tmp;
    }

    // grams
    const int wv = tid >> 6, l = tid & 63, l15 = l & 15, lq = l >> 4;
    const int k8o = lq * 8;
    f32x4 accK[4], accQ4[4];
#pragma unroll
    for (int j = 0; j < 4; ++j) {
        accK[j] = f32x4{0.f, 0.f, 0.f, 0.f};
        accQ4[j] = f32x4{0.f, 0.f, 0.f, 0.f};
    }
#pragma unroll
    for (int kk = 0; kk < 4; ++kk) {
        short8 aK = *(const short8*)(Kb + (wv * 16 + l15) * KSTR + kk * 32 + k8o);
        short8 aQ = *(const short8*)(Qb + (wv * 16 + l15) * KSTR + kk * 32 + k8o);
#pragma unroll
        for (int js = 0; js < 4; ++js) {
            short8 bK = *(const short8*)(Kb + (js * 16 + l15) * KSTR + kk * 32 + k8o);
            accK[js]  = MFMA(aK, bK, accK[js], 0, 0, 0);
            accQ4[js] = MFMA(aQ, bK, accQ4[js], 0, 0, 0);
        }
    }
    ushort* Gc = Gg + (size_t)cid * 4096;
#pragma unroll
    for (int js = 0; js < 4; ++js) {
#pragma unroll
        for (int r = 0; r < 4; ++r) {
            const int t = wv * 16 + lq * 4 + r;
            const int s = js * 16 + l15;
            const float cp = (t > 0) ? cums[t - 1] : 0.f;
            Ef[t * ESTR + s] = (s < t) ? __expf(cp - cums[s]) * accK[js][r] : 0.f;
            const float gv = (s <= t) ? __expf(cums[t] - cums[s]) * accQ4[js][r] : 0.f;
            Gc[t * 64 + s] = f2bf(gv);
        }
    }
    __syncthreads();

    if (tid < 64) {                     // M-solve: lane s owns column s
        const int s = tid;
        for (int r = 0; r < 64; ++r) Mf[r * ESTR + s] = 0.f;
        Mf[s * ESTR + s] = bv[s];
        for (int t = 1; t < 64; ++t) {
            float s0 = 0.f, s1 = 0.f;
            int r = 0;
            for (; r + 1 < t; r += 2) {
                s0 = fmaf(Ef[t * ESTR + r],     Mf[r * ESTR + s],       s0);
                s1 = fmaf(Ef[t * ESTR + r + 1], Mf[(r + 1) * ESTR + s], s1);
            }
            if (r < t) s0 = fmaf(Ef[t * ESTR + r], Mf[r * ESTR + s], s0);
            if (s < t) Mf[t * ESTR + s] = -bv[t] * (s0 + s1);
        }
    }
    __syncthreads();
    ushort* Mc = Mg + (size_t)cid * 4096;
#pragma unroll
    for (int j = 0; j < 16; ++j) {
        const int e = tid + j * 256;
        Mc[e] = f2bf(Mf[(e >> 6) * ESTR + (e & 63)]);
    }
    if (tid < 64) {
        const float cp = (tid > 0) ? cums[tid - 1] : 0.f;
        pug[cid * 64 + tid] = __expf(cp);
        pog[cid * 64 + tid] = __expf(cums[tid]);
        cg [cid * 64 + tid] = __expf(cums[63] - cums[tid]);
        if (tid == 0) dtotg[cid] = __expf(cums[63]);
    }
}

// ===== kernel S (serial): swapped-operand chain; all spills b64+; 2 barriers =
// 32 blocks = bh*2 + half (dv 64-slice); 4 waves, wave owns dv16 x all dk128.
// State kept TRANSPOSED in acc: accS[m]: dk=m*16+lq*4+r, dv=dvw+l15.
__global__ __launch_bounds__(256)
void k_scan2(const ushort* __restrict__ Kst, const ushort* __restrict__ KTst,
             const ushort* __restrict__ Vst, const ushort* __restrict__ Mg,
             const float* __restrict__ pug, const float* __restrict__ cgd,
             const float* __restrict__ dtg,
             ushort* __restrict__ Sst, ushort* __restrict__ Wst)
{
    const int blk = blockIdx.x;          // bh*2 + half
    const int bh = blk >> 1, half = blk & 1;
    const int tid = threadIdx.x;
    const int wv = tid >> 6, l = tid & 63, l15 = l & 15, lq = l >> 4;
    const int k8o = lq * 8;
    const int dvw = wv * 16;             // wave's dv-local base (block = dv64)

    __shared__ ushort Kb[64 * KSTR];     // [t][dk]
    __shared__ ushort KTb[128 * 72];     // [dk][t]
    __shared__ ushort Mb[64 * 72];       // [t'][s]
    __shared__ ushort Vb[64 * 72];       // [dv][t]
    __shared__ ushort Shb[64 * KSTR], Slb[64 * KSTR];  // S [dv][dk] hi/lo
    __shared__ ushort Yb[64 * 72], Wb[64 * 72], Wcb[64 * 72];  // [dv][t]
    __shared__ float puv[64], cv2[64], dts[1];

    f32x4 accS[8];
#pragma unroll
    for (int m = 0; m < 8; ++m) accS[m] = f32x4{0.f, 0.f, 0.f, 0.f};

    uint4 rk[4], rkt[4], rm[2], rv[2];
    float rpu = 0.f, rcv = 0.f, rdt = 0.f;

    auto LOADC = [&](int cc) {
        const int cid = bh * 16 + cc;
        const size_t go = (size_t)cid * 8192;
#pragma unroll
        for (int j = 0; j < 4; ++j) {
            rk[j]  = *(const uint4*)(Kst  + go + (tid + j * 256) * 8);
            rkt[j] = *(const uint4*)(KTst + go + (tid + j * 256) * 8);
        }
#pragma unroll
        for (int j = 0; j < 2; ++j) {
            rm[j] = *(const uint4*)(Mg + (size_t)cid * 4096 + (tid + j * 256) * 8);
            rv[j] = *(const uint4*)(Vst + go + half * 4096 + (tid + j * 256) * 8);
        }
        if (tid < 64) {
            rpu = pug[cid * 64 + tid];
            rcv = cgd[cid * 64 + tid];
            if (tid == 0) rdt = dtg[cid];
        }
    };
    auto WRITEC = [&]() {
#pragma unroll
        for (int j = 0; j < 4; ++j) {
            const int i16 = tid + j * 256;
            *(uint4*)(Kb  + (i16 >> 4) * KSTR + (i16 & 15) * 8) = rk[j];
            *(uint4*)(KTb + (i16 >> 3) * 72   + (i16 & 7) * 8)  = rkt[j];
        }
#pragma unroll
        for (int j = 0; j < 2; ++j) {
            const int i8 = tid + j * 256;
            *(uint4*)(Mb + (i8 >> 3) * 72 + (i8 & 7) * 8) = rm[j];
            *(uint4*)(Vb + (i8 >> 3) * 72 + (i8 & 7) * 8) = rv[j];
        }
        if (tid < 64) {
            puv[tid] = rpu; cv2[tid] = rcv;
            if (tid == 0) dts[0] = rdt;
        }
    };

    LOADC(0); WRITEC();
    __syncthreads();

    for (int c = 0; c < NCK; ++c) {
        if (c + 1 < NCK) LOADC(c + 1);       // in flight through compute

        // ---- B: state (Sᵀ acc) -> Shb/Slb [dv][dk] via b64 writes
#pragma unroll
        for (int m = 0; m < 8; ++m) {
            ushort h4[4], l4v[4];
#pragma unroll
            for (int r = 0; r < 4; ++r) {
                const float sv = accS[m][r];
                const ushort hi = f2bf(sv);
                h4[r] = hi;
                l4v[r] = f2bf(sv - bf2f(hi));
            }
            *(uint2*)(Shb + (dvw + l15) * KSTR + m * 16 + lq * 4) = *(uint2*)h4;
            *(uint2*)(Slb + (dvw + l15) * KSTR + m * 16 + lq * 4) = *(uint2*)l4v;
        }
        // ---- C': Uᵀ = K·Sᵀ (compensated); out lane: t=jj*16+lq*4+r, dv=dvw+l15
        f32x4 accU[4];
#pragma unroll
        for (int jj = 0; jj < 4; ++jj) accU[jj] = f32x4{0.f, 0.f, 0.f, 0.f};
#pragma unroll
        for (int kk = 0; kk < 4; ++kk) {
            short8 sh = *(const short8*)(Shb + (dvw + l15) * KSTR + kk * 32 + k8o);
            short8 sl = *(const short8*)(Slb + (dvw + l15) * KSTR + kk * 32 + k8o);
#pragma unroll
            for (int jj = 0; jj < 4; ++jj) {
                short8 ka = *(const short8*)(Kb + (jj * 16 + l15) * KSTR + kk * 32 + k8o);
                accU[jj] = MFMA(ka, sh, accU[jj], 0, 0, 0);
                accU[jj] = MFMA(ka, sl, accU[jj], 0, 0, 0);
            }
        }
        // ---- D': Y[dv][t] = V - pu⊙U (lane-local; b64 read/write)
#pragma unroll
        for (int jj = 0; jj < 4; ++jj) {
            float pu4[4];
            *(float4*)pu4 = *(const float4*)(puv + jj * 16 + lq * 4);
            ushort v4[4];
            *(uint2*)v4 = *(const uint2*)(Vb + (dvw + l15) * 72 + jj * 16 + lq * 4);
            ushort y4[4];
#pragma unroll
            for (int r = 0; r < 4; ++r)
                y4[r] = f2bf(bf2f(v4[r]) - pu4[r] * accU[jj][r]);
            *(uint2*)(Yb + (dvw + l15) * 72 + jj * 16 + lq * 4) = *(uint2*)y4;
        }
        // ---- E'': Wᵀ = M·Y; out lane: t'=jj*16+lq*4+r, dv=dvw+l15
        f32x4 accW[4];
#pragma unroll
        for (int jj = 0; jj < 4; ++jj) accW[jj] = f32x4{0.f, 0.f, 0.f, 0.f};
#pragma unroll
        for (int kk = 0; kk < 2; ++kk) {
            short8 yb = *(const short8*)(Yb + (dvw + l15) * 72 + kk * 32 + k8o);
#pragma unroll
            for (int jj = 0; jj < 4; ++jj) {
                short8 mf = *(const short8*)(Mb + (jj * 16 + l15) * 72 + kk * 32 + k8o);
                accW[jj] = MFMA(mf, yb, accW[jj], 0, 0, 0);
            }
        }
#pragma unroll
        for (int jj = 0; jj < 4; ++jj) {
            float cv4[4];
            *(float4*)cv4 = *(const float4*)(cv2 + jj * 16 + lq * 4);
            ushort w4[4], wc4[4];
#pragma unroll
            for (int r = 0; r < 4; ++r) {
                const float wl = accW[jj][r];
                w4[r]  = f2bf(wl);
                wc4[r] = f2bf(wl * cv4[r]);
            }
            *(uint2*)(Wb  + (dvw + l15) * 72 + jj * 16 + lq * 4) = *(uint2*)w4;
            *(uint2*)(Wcb + (dvw + l15) * 72 + jj * 16 + lq * 4) = *(uint2*)wc4;
        }
        // ---- G: Sᵀ = dtot·Sᵀ + KT·Wc
        const float dt = dts[0];
#pragma unroll
        for (int m = 0; m < 8; ++m)
#pragma unroll
            for (int r = 0; r < 4; ++r) accS[m][r] *= dt;
#pragma unroll
        for (int kk = 0; kk < 2; ++kk) {
            short8 wc = *(const short8*)(Wcb + (dvw + l15) * 72 + kk * 32 + k8o);
#pragma unroll
            for (int m = 0; m < 8; ++m) {
                short8 kt = *(const short8*)(KTb + (m * 16 + l15) * 72 + kk * 32 + k8o);
                accS[m] = MFMA(kt, wc, accS[m], 0, 0, 0);
            }
        }
        // ---- dumps (wave-local regions of Shb/Wb)
        {
            const int cid = bh * 16 + c;
#pragma unroll
            for (int j = 0; j < 4; ++j) {
                const int idx = l + j * 64;
                const int dvo = idx >> 4, ko = (idx & 15) * 8;
                *(uint4*)(Sst + (size_t)cid * 16384 +
                          (half * 64 + dvw + dvo) * 128 + ko) =
                    *(const uint4*)(Shb + (dvw + dvo) * KSTR + ko);
            }
#pragma unroll
            for (int j = 0; j < 2; ++j) {
                const int idx = l + j * 64;
                const int dvo = idx >> 3, t8 = (idx & 7) * 8;
                *(uint4*)(Wst + (size_t)cid * 8192 +
                          (half * 64 + dvw + dvo) * 64 + t8) =
                    *(const uint4*)(Wb + (dvw + dvo) * 72 + t8);
            }
        }
        __syncthreads();        // all reads of shared bufs done
        if (c + 1 < NCK) WRITEC();
        __syncthreads();        // staged chunk visible
    }
}

// ===== kernel O (parallel): O = po (.) S.Q^T + G.W, fused LayerNorm + gate ====
__global__ __launch_bounds__(256)
void k_out(const ushort* __restrict__ Sst, const ushort* __restrict__ Qst,
           const ushort* __restrict__ Gg, const ushort* __restrict__ Wst,
           const float* __restrict__ pog, const float* __restrict__ g_lin,
           const float* __restrict__ lng, const float* __restrict__ lnb,
           ushort* __restrict__ ogb)
{
    const int cid = blockIdx.x;
    const int bh = cid >> 4, c = cid & 15;
    const int b = bh >> 3, h = bh & 7;
    const int t0 = c * LCH;
    const int tid = threadIdx.x;
    const int wv = tid >> 6, l = tid & 63, l15 = l & 15, lq = l >> 4;
    const int k8o = lq * 8;

    __shared__ ushort Sb[128 * KSTR];
    __shared__ ushort Qb[64 * KSTR];
    __shared__ ushort Gb[64 * 72];
    __shared__ ushort Wqb[128 * 72];
    __shared__ float  Ot[64 * 132];
    __shared__ float  pov[64];

#pragma unroll
    for (int j = 0; j < 8; ++j) {
        const int i16 = tid + j * 256;
        *(uint4*)(Sb + (i16 >> 4) * KSTR + (i16 & 15) * 8) =
            *(const uint4*)(Sst + (size_t)cid * 16384 + i16 * 8);
    }
#pragma unroll
    for (int j = 0; j < 4; ++j) {
        const int i16 = tid + j * 256;
        *(uint4*)(Qb + (i16 >> 4) * KSTR + (i16 & 15) * 8) =
            *(const uint4*)(Qst + (size_t)cid * 8192 + i16 * 8);
        const int i8 = i16;
        *(uint4*)(Wqb + (i8 >> 3) * 72 + (i8 & 7) * 8) =
            *(const uint4*)(Wst + (size_t)cid * 8192 + i8 * 8);
    }
#pragma unroll
    for (int j = 0; j < 2; ++j) {
        const int i8 = tid + j * 256;
        *(uint4*)(Gb + (i8 >> 3) * 72 + (i8 & 7) * 8) =
            *(const uint4*)(Gg + (size_t)cid * 4096 + i8 * 8);
    }
    if (tid < 64) pov[tid] = pog[cid * 64 + tid];
    __syncthreads();

#pragma unroll
    for (int i = 0; i < 2; ++i) {
        const int dvt = wv * 2 + i;
        f32x4 acc[4], acg[4];
#pragma unroll
        for (int jj = 0; jj < 4; ++jj) {
            acc[jj] = f32x4{0.f, 0.f, 0.f, 0.f};
            acg[jj] = f32x4{0.f, 0.f, 0.f, 0.f};
        }
#pragma unroll
        for (int kk = 0; kk < 4; ++kk) {
            short8 sa = *(const short8*)(Sb + (dvt * 16 + l15) * KSTR + kk * 32 + k8o);
#pragma unroll
            for (int jj = 0; jj < 4; ++jj) {
                short8 qb = *(const short8*)(Qb + (jj * 16 + l15) * KSTR + kk * 32 + k8o);
                acc[jj] = MFMA(sa, qb, acc[jj], 0, 0, 0);
            }
        }
#pragma unroll
        for (int kk = 0; kk < 2; ++kk) {
            short8 wa = *(const short8*)(Wqb + (dvt * 16 + l15) * 72 + kk * 32 + k8o);
#pragma unroll
            for (int jj = 0; jj < 4; ++jj) {
                short8 gb = *(const short8*)(Gb + (jj * 16 + l15) * 72 + kk * 32 + k8o);
                acg[jj] = MFMA(wa, gb, acg[jj], 0, 0, 0);
            }
        }
#pragma unroll
        for (int jj = 0; jj < 4; ++jj) {
            const int t = jj * 16 + l15;
            const float po = pov[t];
            float4 o4;
            o4.x = po * acc[jj][0] + acg[jj][0];
            o4.y = po * acc[jj][1] + acg[jj][1];
            o4.z = po * acc[jj][2] + acg[jj][2];
            o4.w = po * acc[jj][3] + acg[jj][3];
            *(float4*)(Ot + t * 132 + dvt * 16 + lq * 4) = o4;
        }
    }
    __syncthreads();

    const int d = l * 2;
    const float lg0 = lng[d], lg1 = lng[d + 1];
    const float lb0 = lnb[d], lb1 = lnb[d + 1];
    const size_t btbase = (size_t)b * TSEQ + t0 + wv * 16;
#pragma unroll 1
    for (int rr = 0; rr < 16; ++rr) {
        const int t = wv * 16 + rr;
        float2 xv = *(const float2*)(Ot + t * 132 + d);
        float s = xv.x + xv.y;
#pragma unroll
        for (int m = 32; m; m >>= 1) s += __shfl_xor(s, m);
        const float mu = s * (1.f / 128.f);
        const float d0 = xv.x - mu, d1 = xv.y - mu;
        float v = d0 * d0 + d1 * d1;
#pragma unroll
        for (int m = 32; m; m >>= 1) v += __shfl_xor(v, m);
        const float inv = rsqrtf(v * (1.f / 128.f) + 1e-5f);
        const float* gp = g_lin + (btbase + rr) * HID_ + h * DV;
        const float g0 = sig_(gp[d]), g1 = sig_(gp[d + 1]);
        const float y0 = (d0 * inv * lg0 + lb0) * g0;
        const float y1 = (d1 * inv * lg1 + lb1) * g1;
        *(uint*)(ogb + (btbase + rr) * HID_ + h * DV + d) = pk2(y0, y1);
    }
}

extern "C" void kernel_launch(void* const* d_in, const int* in_sizes, int n_in,
                              void* d_out, int out_size, void* d_ws, size_t ws_size,
                              hipStream_t stream)
{
    const float* x   = (const float*)d_in[0];
    const float* Wq  = (const float*)d_in[1];
    const float* Wk  = (const float*)d_in[2];
    const float* Wv  = (const float*)d_in[3];
    const float* cqw = (const float*)d_in[4];
    const float* cqb = (const float*)d_in[5];
    const float* ckw = (const float*)d_in[6];
    const float* ckb = (const float*)d_in[7];
    const float* cvw = (const float*)d_in[8];
    const float* cvb = (const float*)d_in[9];
    const float* Wa  = (const float*)d_in[10];
    const float* ba  = (const float*)d_in[11];
    const float* Wb  = (const float*)d_in[12];
    const float* bb  = (const float*)d_in[13];
    const float* Wg  = (const float*)d_in[14];
    const float* Wo  = (const float*)d_in[15];
    const float* lng = (const float*)d_in[16];
    const float* lnb = (const float*)d_in[17];
    float* out = (float*)d_out;
    float* ws  = (float*)d_ws;

    float* q_lin = ws;                       // f32; dead after stageprep; ogb reuses
    float* k_lin = ws + 1 * (size_t)SZf;     // f32; dead after stageprep; WoT reuses
    float* v_lin = ws + 2 * (size_t)SZf;     // f32; dead after stageprep
    float* g_lin = ws + 3 * (size_t)SZf;     // read by k_out
    float* o_buf = ws + 4 * (size_t)SZf;     // WT4 -> conv scratch -> Sst
    float* aT    = ws + 5 * (size_t)SZf;
    float* bT    = aT + 16 * TSEQ;
    float* pug   = bT + 16 * TSEQ;
    float* pog   = pug + 256 * 64;
    float* cgd   = pog + 256 * 64;
    float* dtg   = cgd + 256 * 64;

    float*  tail = ws + 5 * (size_t)SZf + 131072;
    ushort* Kst  = (ushort*)tail;                    // 4MB
    ushort* Qst  = Kst + (size_t)256 * 8192;         // 4MB
    ushort* xbf  = Qst + (size_t)256 * 8192;         // 4MB; dead after gemm4
    ushort* Vst  = xbf;                              // reuse: written by stageprep
    ushort* KTst = xbf + (size_t)256 * 8192;         // 4MB (new)

    ushort* WT4 = (ushort*)o_buf;            // dead after gemm4
    ushort* WoT = (ushort*)k_lin;            // written after stageprep
    ushort* ogb = (ushort*)q_lin;            // bf16 LN output (4MB)
    ushort* Sst = (ushort*)o_buf;            // 8MB: 256 x [128][128] bf16
    ushort* Mg  = (ushort*)out;              // 2MB
    ushort* Gg  = Mg + (size_t)256 * 4096;   // 2MB
    ushort* Wst = Gg + (size_t)256 * 4096;   // 4MB -> fills d_out exactly

    k_x2bf<<<1024, 256, 0, stream>>>(x, xbf);
    k_wT<<<dim3(16, 16, 4), 256, 0, stream>>>(Wq, Wk, Wv, Wg, WT4);
    k_gemm4<<<dim3(8, 16, 4), 256, 0, stream>>>(xbf, WT4, ws);
    k_ab<<<ROWS, 64, 0, stream>>>(x, Wa, ba, Wb, bb, aT, bT);
    k_conv_save<<<dim3(15, 2, 3), 256, 0, stream>>>(q_lin, k_lin, v_lin, o_buf);
    k_conv_apply<<<dim3(64, 2, 3), 256, 0, stream>>>(q_lin, k_lin, v_lin, o_buf,
                                                     cqw, cqb, ckw, ckb, cvw, cvb);
    k_stageprep<<<256, 256, 0, stream>>>(k_lin, q_lin, v_lin, aT, bT,
                                         Kst, Qst, Vst, KTst, Mg, Gg,
                                         pug, pog, cgd, dtg);
    k_wT<<<dim3(16, 16, 1), 256, 0, stream>>>(Wo, Wo, Wo, Wo, WoT);
    k_scan2<<<32, 256, 0, stream>>>(Kst, KTst, Vst, Mg, pug, cgd, dtg, Sst, Wst);
    k_out<<<256, 256, 0, stream>>>(Sst, Qst, Gg, Wst, pog, g_lin, lng, lnb, ogb);
    k_gemm1<<<dim3(8, 16), 256, 0, stream>>>(ogb, WoT, out);
}

// Round 12
// 231.334 us; speedup vs baseline: 1.4509x; 1.0004x over previous
//
#include <hip/hip_runtime.h>

#define TSEQ 1024
#define HID_ 1024
#define NH 8
#define DK 128
#define DV 128
#define ROWS 2048               // B*T
#define SZf (ROWS * HID_)       // floats per [2048,1024] matrix
#define LCH 64                  // scan chunk length
#define NCK 16                  // chunks per (b,h)
#define KSTR 136                // bf16 LDS stride for [64][128] tiles
#define ESTR 65

typedef __attribute__((ext_vector_type(8))) short short8;
typedef __attribute__((ext_vector_type(4))) float f32x4;
#define MFMA __builtin_amdgcn_mfma_f32_16x16x32_bf16

__device__ __forceinline__ float sig_(float x) { return 1.f / (1.f + __expf(-x)); }

__device__ __forceinline__ ushort f2bf(float f) {   // RNE f32->bf16
    unsigned int u = __builtin_bit_cast(unsigned int, f);
    u += 0x7FFF + ((u >> 16) & 1);
    return (ushort)(u >> 16);
}
__device__ __forceinline__ float bf2f(ushort u) {
    return __builtin_bit_cast(float, ((unsigned int)u) << 16);
}
__device__ __forceinline__ unsigned int pk2(float lo, float hi) {
    return (unsigned int)f2bf(lo) | ((unsigned int)f2bf(hi) << 16);
}

// async global->LDS, 16B per lane; dst = wave-uniform base (+lane*16 by HW)
__device__ __forceinline__ void gload16(const void* g, void* l) {
    __builtin_amdgcn_global_load_lds(
        (const __attribute__((address_space(1))) unsigned int*)g,
        (__attribute__((address_space(3))) unsigned int*)l, 16, 0, 0);
}

// ---------------- x -> bf16 ----------------
__global__ __launch_bounds__(256)
void k_x2bf(const float* __restrict__ x, ushort* __restrict__ xb)
{
    const size_t i8 = (size_t)blockIdx.x * 256 + threadIdx.x;   // grid 1024
    float4 v0 = *(const float4*)(x + i8 * 8);
    float4 v1 = *(const float4*)(x + i8 * 8 + 4);
    uint4 o;
    o.x = pk2(v0.x, v0.y); o.y = pk2(v0.z, v0.w);
    o.z = pk2(v1.x, v1.y); o.w = pk2(v1.z, v1.w);
    *(uint4*)(xb + i8 * 8) = o;
}

// ---------------- weight transpose+convert: W f32 [K][N] -> WT bf16 [N][K] ----
__global__ __launch_bounds__(256)
void k_wT(const float* __restrict__ s0, const float* __restrict__ s1,
          const float* __restrict__ s2, const float* __restrict__ s3,
          ushort* __restrict__ dst)
{
    const int z = blockIdx.z;
    const float* W = (z == 0) ? s0 : (z == 1) ? s1 : (z == 2) ? s2 : s3;
    ushort* WT = dst + (size_t)z * (1024 * 1024);
    __shared__ float t[64][65];
    const int n0 = blockIdx.x * 64, k0 = blockIdx.y * 64;
    const int rr = threadIdx.x >> 4, cc = threadIdx.x & 15;
#pragma unroll
    for (int i = 0; i < 4; ++i) {
        const int row = i * 16 + rr;
        float4 v = *(const float4*)(W + (size_t)(k0 + row) * 1024 + n0 + cc * 4);
        t[row][cc * 4 + 0] = v.x; t[row][cc * 4 + 1] = v.y;
        t[row][cc * 4 + 2] = v.z; t[row][cc * 4 + 3] = v.w;
    }
    __syncthreads();
#pragma unroll
    for (int i = 0; i < 4; ++i) {
        const int n = i * 16 + rr;
        const int kc = cc * 4;
        ushort4 o;
        o.x = f2bf(t[kc + 0][n]); o.y = f2bf(t[kc + 1][n]);
        o.z = f2bf(t[kc + 2][n]); o.w = f2bf(t[kc + 3][n]);
        *(ushort4*)(WT + (size_t)(n0 + n) * 1024 + k0 + kc) = o;
    }
}

// ------ bf16 MFMA GEMM, m97 structure: global_load_lds(16B) direct staging ----
// LDS [128][32] bf16 LINEAR (gload_lds needs contiguous dest); 2 barriers/K-step.
__device__ __forceinline__ void gemm_tile_mfma(const ushort* __restrict__ A,
                                               const ushort* __restrict__ BT,
                                               float* __restrict__ C,
                                               int brow, int bcol)
{
    __shared__ ushort As[128 * 32];
    __shared__ ushort Bs[128 * 32];
    const int tid  = threadIdx.x;
    const int lane = tid & 63;
    const int wv   = tid >> 6;
    const int wm   = (wv >> 1) * 64;
    const int wn   = (wv & 1) * 64;
    const int l15  = lane & 15;
    const int k8   = (lane >> 4) * 8;
    const int row0 = (tid >> 2);          // i>>2 for i=tid
    const int q0   = (tid & 3) * 8;

    f32x4 acc[4][4];
#pragma unroll
    for (int i = 0; i < 4; ++i)
#pragma unroll
        for (int j = 0; j < 4; ++j)
#pragma unroll
            for (int e = 0; e < 4; ++e) acc[i][j][e] = 0.f;

    for (int k0 = 0; k0 < 1024; k0 += 32) {
        __syncthreads();                   // prior frags consumed
#pragma unroll
        for (int j = 0; j < 2; ++j) {
            const int i   = j * 256 + tid;
            const int row = j * 64 + row0; // (j*256+tid)>>2
            const int i0  = j * 256 + wv * 64;         // wave-uniform LDS base
            gload16(A  + (size_t)(brow + row) * 1024 + k0 + q0, As + i0 * 8);
            gload16(BT + (size_t)(bcol + row) * 1024 + k0 + q0, Bs + i0 * 8);
            (void)i;
        }
        __syncthreads();                   // vmcnt(0) drain -> data visible
        short8 af[4], bf[4];
#pragma unroll
        for (int i = 0; i < 4; ++i)
            af[i] = *(const short8*)(As + (wm + i * 16 + l15) * 32 + k8);
#pragma unroll
        for (int j = 0; j < 4; ++j)
            bf[j] = *(const short8*)(Bs + (wn + j * 16 + l15) * 32 + k8);
#pragma unroll
        for (int i = 0; i < 4; ++i)
#pragma unroll
            for (int j = 0; j < 4; ++j)
                acc[i][j] = MFMA(af[i], bf[j], acc[i][j], 0, 0, 0);
    }
    const int l4 = lane >> 4;
#pragma unroll
    for (int i = 0; i < 4; ++i)
#pragma unroll
        for (int j = 0; j < 4; ++j)
#pragma unroll
            for (int r = 0; r < 4; ++r)
                C[(size_t)(brow + wm + i * 16 + l4 * 4 + r) * 1024 +
                  bcol + wn + j * 16 + l15] = acc[i][j][r];
}

__global__ __launch_bounds__(256)
void k_gemm4(const ushort* __restrict__ A, const ushort* __restrict__ WT,
             float* __restrict__ Cbase)
{
    const ushort* BT = WT + (size_t)blockIdx.z * (1024 * 1024);
    float* C = Cbase + (size_t)blockIdx.z * SZf;
    gemm_tile_mfma(A, BT, C, blockIdx.y * 128, blockIdx.x * 128);
}

__global__ __launch_bounds__(256)
void k_gemm1(const ushort* __restrict__ A, const ushort* __restrict__ BT,
             float* __restrict__ C)
{
    gemm_tile_mfma(A, BT, C, blockIdx.y * 128, blockIdx.x * 128);
}

// -------- alpha/beta small GEMM + sigmoid; writes TRANSPOSED [bh][t] --------
// 256-thread blocks, one wave per row (4 rows/block).
__global__ __launch_bounds__(256)
void k_ab(const float* __restrict__ x, const float* __restrict__ Wa,
          const float* __restrict__ ba, const float* __restrict__ Wb,
          const float* __restrict__ bb, float* __restrict__ aT,
          float* __restrict__ bT)
{
    const int r = blockIdx.x * 4 + (threadIdx.x >> 6);   // r = b*1024 + t
    const int lane = threadIdx.x & 63;
    const int b = r >> 10, t = r & 1023;
    const float* xr = x + (size_t)r * HID_;
    float acc[16];
#pragma unroll
    for (int n = 0; n < 16; ++n) acc[n] = 0.f;
    for (int c = lane; c < HID_; c += 64) {
        const float xv = xr[c];
        const float* wa = Wa + c * 8;
        const float* wb = Wb + c * 8;
#pragma unroll
        for (int n = 0; n < 8; ++n) {
            acc[n]     = fmaf(xv, wa[n], acc[n]);
            acc[8 + n] = fmaf(xv, wb[n], acc[8 + n]);
        }
    }
#pragma unroll
    for (int n = 0; n < 16; ++n) {
#pragma unroll
        for (int m = 32; m; m >>= 1) acc[n] += __shfl_xor(acc[n], m);
    }
    if (lane < 8) {
        aT[(size_t)(b * 8 + lane) * TSEQ + t] = sig_(acc[lane] + ba[lane]);
        bT[(size_t)(b * 8 + lane) * TSEQ + t] = sig_(acc[8 + lane] + bb[lane]);
    }
}

// -------- causal depthwise conv K=4 + SiLU (+scale), in-place, T-parallel ----
__global__ __launch_bounds__(256)
void k_conv_save(const float* __restrict__ q, const float* __restrict__ k,
                 const float* __restrict__ v, float* __restrict__ scr)
{
    const int z = blockIdx.z, b = blockIdx.y, j = blockIdx.x + 1;
    const float* y = (z == 0) ? q : (z == 1) ? k : v;
    float* d = scr + ((size_t)(z * 2 + b) * 15 + (j - 1)) * 3 * 1024;
    const float* s = y + ((size_t)b * TSEQ + j * 64 - 3) * HID_;
    for (int i = threadIdx.x; i < 3 * 1024; i += 256)
        d[i] = s[i];
}

__global__ __launch_bounds__(256)
void k_conv_apply(float* __restrict__ q, float* __restrict__ k, float* __restrict__ v,
                  const float* __restrict__ scr,
                  const float* __restrict__ wq, const float* __restrict__ bq,
                  const float* __restrict__ wk, const float* __restrict__ bk,
                  const float* __restrict__ wv, const float* __restrict__ bv)
{
    const int z = blockIdx.z, b = blockIdx.y;
    const int j = blockIdx.x >> 2, cg = blockIdx.x & 3;
    float* y          = (z == 0) ? q  : (z == 1) ? k  : v;
    const float* w    = (z == 0) ? wq : (z == 1) ? wk : wv;
    const float* bias = (z == 0) ? bq : (z == 1) ? bk : bv;
    const float scale = (z == 1) ? 0.08838834764831845f : 1.f;
    const int c = cg * 256 + threadIdx.x;
    const float w0 = w[c * 4], w1 = w[c * 4 + 1], w2 = w[c * 4 + 2], w3 = w[c * 4 + 3];
    const float bs = bias[c];
    float y0 = 0.f, y1 = 0.f, y2 = 0.f;
    if (j > 0) {
        const float* s = scr + ((size_t)(z * 2 + b) * 15 + (j - 1)) * 3 * 1024 + c;
        y0 = s[0]; y1 = s[1024]; y2 = s[2048];
    }
    float* yp = y + ((size_t)b * TSEQ + j * 64) * HID_ + c;
#pragma unroll 4
    for (int t = 0; t < 64; ++t) {
        float y3  = yp[(size_t)t * HID_];
        float acc = fmaf(w0, y0, fmaf(w1, y1, fmaf(w2, y2, fmaf(w3, y3, bs))));
        float sv  = acc * sig_(acc) * scale;
        yp[(size_t)t * HID_] = sv;
        y0 = y1; y1 = y2; y2 = y3;
    }
}

// ========== k_stageprep: stage K/Q/V/KT (bf16) + M, G, decays per chunk ======
__global__ __launch_bounds__(256)
void k_stageprep(const float* __restrict__ klin, const float* __restrict__ qlin,
                 const float* __restrict__ vlin,
                 const float* __restrict__ aT, const float* __restrict__ bT,
                 ushort* __restrict__ Kst, ushort* __restrict__ Qst,
                 ushort* __restrict__ Vst, ushort* __restrict__ KTst,
                 ushort* __restrict__ Mg, ushort* __restrict__ Gg,
                 float* __restrict__ pug, float* __restrict__ pog,
                 float* __restrict__ cg, float* __restrict__ dtotg)
{
    const int cid = blockIdx.x;          // bh*16 + c
    const int bh = cid >> 4, c = cid & 15;
    const int b = bh >> 3, h = bh & 7;
    const int tid = threadIdx.x;
    const int t0 = c * LCH;

    __shared__ ushort Kb[64 * KSTR], Qb[64 * KSTR];
    __shared__ ushort Vl[128 * 72];
    __shared__ float Ef[64 * ESTR];
    __shared__ float Mf[64 * ESTR];
    __shared__ float cums[64], bv[64];

    if (tid < 64) {
        const float a = aT[(size_t)bh * TSEQ + t0 + tid];
        bv[tid] = bT[(size_t)bh * TSEQ + t0 + tid];
        float cs = __logf(a);
#pragma unroll
        for (int d = 1; d < 64; d <<= 1) {
            float pv = __shfl_up(cs, d);
            if (tid >= d) cs += pv;
        }
        cums[tid] = cs;
    }
    const float* kb = klin + ((size_t)b * TSEQ + t0) * HID_ + h * DK;
    const float* qb = qlin + ((size_t)b * TSEQ + t0) * HID_ + h * DK;
    const float* vb = vlin + ((size_t)b * TSEQ + t0) * HID_ + h * DV;
    const size_t go = (size_t)cid * 8192;
#pragma unroll
    for (int j = 0; j < 8; ++j) {
        const int i4 = tid + j * 256;
        const int row = i4 >> 5, c4 = i4 & 31;
        float4 kv = *(const float4*)(kb + (size_t)row * HID_ + c4 * 4);
        float4 qv = *(const float4*)(qb + (size_t)row * HID_ + c4 * 4);
        float4 vv = *(const float4*)(vb + (size_t)row * HID_ + c4 * 4);
        uint2 kp; kp.x = pk2(kv.x, kv.y); kp.y = pk2(kv.z, kv.w);
        uint2 qp; qp.x = pk2(qv.x, qv.y); qp.y = pk2(qv.z, qv.w);
        *(uint2*)(Kst + go + row * 128 + c4 * 4) = kp;
        *(uint2*)(Qst + go + row * 128 + c4 * 4) = qp;
        *(uint2*)(Kb + row * KSTR + c4 * 4) = kp;
        *(uint2*)(Qb + row * KSTR + c4 * 4) = qp;
        const int dv0 = c4 * 4;
        Vl[(dv0 + 0) * 72 + row] = f2bf(vv.x);
        Vl[(dv0 + 1) * 72 + row] = f2bf(vv.y);
        Vl[(dv0 + 2) * 72 + row] = f2bf(vv.z);
        Vl[(dv0 + 3) * 72 + row] = f2bf(vv.w);
    }
    __syncthreads();

    // V-dump [dv][t] and KT-dump [dk][t]
#pragma unroll
    for (int j = 0; j < 4; ++j) {
        const int idx = tid + j * 256;
        const int dv = idx >> 3, tq = (idx & 7) * 8;
        *(uint4*)(Vst + go + dv * 64 + tq) = *(const uint4*)(Vl + dv * 72 + tq);
        const int dk = idx >> 3, tt = (idx & 7) * 8;
        ushort tmp[8];
#pragma unroll
        for (int e = 0; e < 8; ++e) tmp[e] = Kb[(tt + e) * KSTR + dk];
        *(uint4*)(KTst + go + dk * 64 + tt) = *(uint4*)tmp;
    }

    // grams
    const int wv = tid >> 6, l = tid & 63, l15 = l & 15, lq = l >> 4;
    const int k8o = lq * 8;
    f32x4 accK[4], accQ4[4];
#pragma unroll
    for (int j = 0; j < 4; ++j) {
        accK[j] = f32x4{0.f, 0.f, 0.f, 0.f};
        accQ4[j] = f32x4{0.f, 0.f, 0.f, 0.f};
    }
#pragma unroll
    for (int kk = 0; kk < 4; ++kk) {
        short8 aK = *(const short8*)(Kb + (wv * 16 + l15) * KSTR + kk * 32 + k8o);
        short8 aQ = *(const short8*)(Qb + (wv * 16 + l15) * KSTR + kk * 32 + k8o);
#pragma unroll
        for (int js = 0; js < 4; ++js) {
            short8 bK = *(const short8*)(Kb + (js * 16 + l15) * KSTR + kk * 32 + k8o);
            accK[js]  = MFMA(aK, bK, accK[js], 0, 0, 0);
            accQ4[js] = MFMA(aQ, bK, accQ4[js], 0, 0, 0);
        }
    }
    ushort* Gc = Gg + (size_t)cid * 4096;
#pragma unroll
    for (int js = 0; js < 4; ++js) {
#pragma unroll
        for (int r = 0; r < 4; ++r) {
            const int t = wv * 16 + lq * 4 + r;
            const int s = js * 16 + l15;
            const float cp = (t > 0) ? cums[t - 1] : 0.f;
            Ef[t * ESTR + s] = (s < t) ? __expf(cp - cums[s]) * accK[js][r] : 0.f;
            const float gv = (s <= t) ? __expf(cums[t] - cums[s]) * accQ4[js][r] : 0.f;
            Gc[t * 64 + s] = f2bf(gv);
        }
    }
    __syncthreads();

    if (tid < 64) {                     // M-solve: lane s owns column s
        const int s = tid;
        for (int r = 0; r < 64; ++r) Mf[r * ESTR + s] = 0.f;
        Mf[s * ESTR + s] = bv[s];
        for (int t = 1; t < 64; ++t) {
            float s0 = 0.f, s1 = 0.f;
            int r = 0;
            for (; r + 1 < t; r += 2) {
                s0 = fmaf(Ef[t * ESTR + r],     Mf[r * ESTR + s],       s0);
                s1 = fmaf(Ef[t * ESTR + r + 1], Mf[(r + 1) * ESTR + s], s1);
            }
            if (r < t) s0 = fmaf(Ef[t * ESTR + r], Mf[r * ESTR + s], s0);
            if (s < t) Mf[t * ESTR + s] = -bv[t] * (s0 + s1);
        }
    }
    __syncthreads();
    ushort* Mc = Mg + (size_t)cid * 4096;
#pragma unroll
    for (int j = 0; j < 16; ++j) {
        const int e = tid + j * 256;
        Mc[e] = f2bf(Mf[(e >> 6) * ESTR + (e & 63)]);
    }
    if (tid < 64) {
        const float cp = (tid > 0) ? cums[tid - 1] : 0.f;
        pug[cid * 64 + tid] = __expf(cp);
        pog[cid * 64 + tid] = __expf(cums[tid]);
        cg [cid * 64 + tid] = __expf(cums[63] - cums[tid]);
        if (tid == 0) dtotg[cid] = __expf(cums[63]);
    }
}

// ===== kernel S (serial): swapped-operand chain; all spills b64+; 2 barriers =
__global__ __launch_bounds__(256)
void k_scan2(const ushort* __restrict__ Kst, const ushort* __restrict__ KTst,
             const ushort* __restrict__ Vst, const ushort* __restrict__ Mg,
             const float* __restrict__ pug, const float* __restrict__ cgd,
             const float* __restrict__ dtg,
             ushort* __restrict__ Sst, ushort* __restrict__ Wst)
{
    const int blk = blockIdx.x;          // bh*2 + half
    const int bh = blk >> 1, half = blk & 1;
    const int tid = threadIdx.x;
    const int wv = tid >> 6, l = tid & 63, l15 = l & 15, lq = l >> 4;
    const int k8o = lq * 8;
    const int dvw = wv * 16;

    __shared__ ushort Kb[64 * KSTR];
    __shared__ ushort KTb[128 * 72];
    __shared__ ushort Mb[64 * 72];
    __shared__ ushort Vb[64 * 72];
    __shared__ ushort Shb[64 * KSTR], Slb[64 * KSTR];
    __shared__ ushort Yb[64 * 72], Wb[64 * 72], Wcb[64 * 72];
    __shared__ float puv[64], cv2[64], dts[1];

    f32x4 accS[8];
#pragma unroll
    for (int m = 0; m < 8; ++m) accS[m] = f32x4{0.f, 0.f, 0.f, 0.f};

    uint4 rk[4], rkt[4], rm[2], rv[2];
    float rpu = 0.f, rcv = 0.f, rdt = 0.f;

    auto LOADC = [&](int cc) {
        const int cid = bh * 16 + cc;
        const size_t go = (size_t)cid * 8192;
#pragma unroll
        for (int j = 0; j < 4; ++j) {
            rk[j]  = *(const uint4*)(Kst  + go + (tid + j * 256) * 8);
            rkt[j] = *(const uint4*)(KTst + go + (tid + j * 256) * 8);
        }
#pragma unroll
        for (int j = 0; j < 2; ++j) {
            rm[j] = *(const uint4*)(Mg + (size_t)cid * 4096 + (tid + j * 256) * 8);
            rv[j] = *(const uint4*)(Vst + go + half * 4096 + (tid + j * 256) * 8);
        }
        if (tid < 64) {
            rpu = pug[cid * 64 + tid];
            rcv = cgd[cid * 64 + tid];
            if (tid == 0) rdt = dtg[cid];
        }
    };
    auto WRITEC = [&]() {
#pragma unroll
        for (int j = 0; j < 4; ++j) {
            const int i16 = tid + j * 256;
            *(uint4*)(Kb  + (i16 >> 4) * KSTR + (i16 & 15) * 8) = rk[j];
            *(uint4*)(KTb + (i16 >> 3) * 72   + (i16 & 7) * 8)  = rkt[j];
        }
#pragma unroll
        for (int j = 0; j < 2; ++j) {
            const int i8 = tid + j * 256;
            *(uint4*)(Mb + (i8 >> 3) * 72 + (i8 & 7) * 8) = rm[j];
            *(uint4*)(Vb + (i8 >> 3) * 72 + (i8 & 7) * 8) = rv[j];
        }
        if (tid < 64) {
            puv[tid] = rpu; cv2[tid] = rcv;
            if (tid == 0) dts[0] = rdt;
        }
    };

    LOADC(0); WRITEC();
    __syncthreads();

    for (int c = 0; c < NCK; ++c) {
        if (c + 1 < NCK) LOADC(c + 1);

        // ---- B: state (S^T acc) -> Shb/Slb [dv][dk] via b64 writes
#pragma unroll
        for (int m = 0; m < 8; ++m) {
            ushort h4[4], l4v[4];
#pragma unroll
            for (int r = 0; r < 4; ++r) {
                const float sv = accS[m][r];
                const ushort hi = f2bf(sv);
                h4[r] = hi;
                l4v[r] = f2bf(sv - bf2f(hi));
            }
            *(uint2*)(Shb + (dvw + l15) * KSTR + m * 16 + lq * 4) = *(uint2*)h4;
            *(uint2*)(Slb + (dvw + l15) * KSTR + m * 16 + lq * 4) = *(uint2*)l4v;
        }
        // ---- C': U^T = K.S^T (compensated)
        f32x4 accU[4];
#pragma unroll
        for (int jj = 0; jj < 4; ++jj) accU[jj] = f32x4{0.f, 0.f, 0.f, 0.f};
#pragma unroll
        for (int kk = 0; kk < 4; ++kk) {
            short8 sh = *(const short8*)(Shb + (dvw + l15) * KSTR + kk * 32 + k8o);
            short8 sl = *(const short8*)(Slb + (dvw + l15) * KSTR + kk * 32 + k8o);
#pragma unroll
            for (int jj = 0; jj < 4; ++jj) {
                short8 ka = *(const short8*)(Kb + (jj * 16 + l15) * KSTR + kk * 32 + k8o);
                accU[jj] = MFMA(ka, sh, accU[jj], 0, 0, 0);
                accU[jj] = MFMA(ka, sl, accU[jj], 0, 0, 0);
            }
        }
        // ---- D': Y[dv][t] = V - pu (.) U (lane-local b64)
#pragma unroll
        for (int jj = 0; jj < 4; ++jj) {
            float pu4[4];
            *(float4*)pu4 = *(const float4*)(puv + jj * 16 + lq * 4);
            ushort v4[4];
            *(uint2*)v4 = *(const uint2*)(Vb + (dvw + l15) * 72 + jj * 16 + lq * 4);
            ushort y4[4];
#pragma unroll
            for (int r = 0; r < 4; ++r)
                y4[r] = f2bf(bf2f(v4[r]) - pu4[r] * accU[jj][r]);
            *(uint2*)(Yb + (dvw + l15) * 72 + jj * 16 + lq * 4) = *(uint2*)y4;
        }
        // ---- E'': W^T = M.Y
        f32x4 accW[4];
#pragma unroll
        for (int jj = 0; jj < 4; ++jj) accW[jj] = f32x4{0.f, 0.f, 0.f, 0.f};
#pragma unroll
        for (int kk = 0; kk < 2; ++kk) {
            short8 yb = *(const short8*)(Yb + (dvw + l15) * 72 + kk * 32 + k8o);
#pragma unroll
            for (int jj = 0; jj < 4; ++jj) {
                short8 mf = *(const short8*)(Mb + (jj * 16 + l15) * 72 + kk * 32 + k8o);
                accW[jj] = MFMA(mf, yb, accW[jj], 0, 0, 0);
            }
        }
#pragma unroll
        for (int jj = 0; jj < 4; ++jj) {
            float cv4[4];
            *(float4*)cv4 = *(const float4*)(cv2 + jj * 16 + lq * 4);
            ushort w4[4], wc4[4];
#pragma unroll
            for (int r = 0; r < 4; ++r) {
                const float wl = accW[jj][r];
                w4[r]  = f2bf(wl);
                wc4[r] = f2bf(wl * cv4[r]);
            }
            *(uint2*)(Wb  + (dvw + l15) * 72 + jj * 16 + lq * 4) = *(uint2*)w4;
            *(uint2*)(Wcb + (dvw + l15) * 72 + jj * 16 + lq * 4) = *(uint2*)wc4;
        }
        // ---- G: S^T = dtot.S^T + KT.Wc
        const float dt = dts[0];
#pragma unroll
        for (int m = 0; m < 8; ++m)
#pragma unroll
            for (int r = 0; r < 4; ++r) accS[m][r] *= dt;
#pragma unroll
        for (int kk = 0; kk < 2; ++kk) {
            short8 wc = *(const short8*)(Wcb + (dvw + l15) * 72 + kk * 32 + k8o);
#pragma unroll
            for (int m = 0; m < 8; ++m) {
                short8 kt = *(const short8*)(KTb + (m * 16 + l15) * 72 + kk * 32 + k8o);
                accS[m] = MFMA(kt, wc, accS[m], 0, 0, 0);
            }
        }
        // ---- dumps (wave-local regions of Shb/Wb)
        {
            const int cid = bh * 16 + c;
#pragma unroll
            for (int j = 0; j < 4; ++j) {
                const int idx = l + j * 64;
                const int dvo = idx >> 4, ko = (idx & 15) * 8;
                *(uint4*)(Sst + (size_t)cid * 16384 +
                          (half * 64 + dvw + dvo) * 128 + ko) =
                    *(const uint4*)(Shb + (dvw + dvo) * KSTR + ko);
            }
#pragma unroll
            for (int j = 0; j < 2; ++j) {
                const int idx = l + j * 64;
                const int dvo = idx >> 3, t8 = (idx & 7) * 8;
                *(uint4*)(Wst + (size_t)cid * 8192 +
                          (half * 64 + dvw + dvo) * 64 + t8) =
                    *(const uint4*)(Wb + (dvw + dvo) * 72 + t8);
            }
        }
        __syncthreads();
        if (c + 1 < NCK) WRITEC();
        __syncthreads();
    }
}

// ===== kernel O (parallel): O = po (.) S.Q^T + G.W, fused LayerNorm + gate ====
__global__ __launch_bounds__(256)
void k_out(const ushort* __restrict__ Sst, const ushort* __restrict__ Qst,
           const ushort* __restrict__ Gg, const ushort* __restrict__ Wst,
           const float* __restrict__ pog, const float* __restrict__ g_lin,
           const float* __restrict__ lng, const float* __restrict__ lnb,
           ushort* __restrict__ ogb)
{
    const int cid = blockIdx.x;
    const int bh = cid >> 4, c = cid & 15;
    const int b = bh >> 3, h = bh & 7;
    const int t0 = c * LCH;
    const int tid = threadIdx.x;
    const int wv = tid >> 6, l = tid & 63, l15 = l & 15, lq = l >> 4;
    const int k8o = lq * 8;

    __shared__ ushort Sb[128 * KSTR];
    __shared__ ushort Qb[64 * KSTR];
    __shared__ ushort Gb[64 * 72];
    __shared__ ushort Wqb[128 * 72];
    __shared__ float  Ot[64 * 132];
    __shared__ float  pov[64];

#pragma unroll
    for (int j = 0; j < 8; ++j) {
        const int i16 = tid + j * 256;
        *(uint4*)(Sb + (i16 >> 4) * KSTR + (i16 & 15) * 8) =
            *(const uint4*)(Sst + (size_t)cid * 16384 + i16 * 8);
    }
#pragma unroll
    for (int j = 0; j < 4; ++j) {
        const int i16 = tid + j * 256;
        *(uint4*)(Qb + (i16 >> 4) * KSTR + (i16 & 15) * 8) =
            *(const uint4*)(Qst + (size_t)cid * 8192 + i16 * 8);
        const int i8 = i16;
        *(uint4*)(Wqb + (i8 >> 3) * 72 + (i8 & 7) * 8) =
            *(const uint4*)(Wst + (size_t)cid * 8192 + i8 * 8);
    }
#pragma unroll
    for (int j = 0; j < 2; ++j) {
        const int i8 = tid + j * 256;
        *(uint4*)(Gb + (i8 >> 3) * 72 + (i8 & 7) * 8) =
            *(const uint4*)(Gg + (size_t)cid * 4096 + i8 * 8);
    }
    if (tid < 64) pov[tid] = pog[cid * 64 + tid];
    __syncthreads();

#pragma unroll
    for (int i = 0; i < 2; ++i) {
        const int dvt = wv * 2 + i;
        f32x4 acc[4], acg[4];
#pragma unroll
        for (int jj = 0; jj < 4; ++jj) {
            acc[jj] = f32x4{0.f, 0.f, 0.f, 0.f};
            acg[jj] = f32x4{0.f, 0.f, 0.f, 0.f};
        }
#pragma unroll
        for (int kk = 0; kk < 4; ++kk) {
            short8 sa = *(const short8*)(Sb + (dvt * 16 + l15) * KSTR + kk * 32 + k8o);
#pragma unroll
            for (int jj = 0; jj < 4; ++jj) {
                short8 qb = *(const short8*)(Qb + (jj * 16 + l15) * KSTR + kk * 32 + k8o);
                acc[jj] = MFMA(sa, qb, acc[jj], 0, 0, 0);
            }
        }
#pragma unroll
        for (int kk = 0; kk < 2; ++kk) {
            short8 wa = *(const short8*)(Wqb + (dvt * 16 + l15) * 72 + kk * 32 + k8o);
#pragma unroll
            for (int jj = 0; jj < 4; ++jj) {
                short8 gb = *(const short8*)(Gb + (jj * 16 + l15) * 72 + kk * 32 + k8o);
                acg[jj] = MFMA(wa, gb, acg[jj], 0, 0, 0);
            }
        }
#pragma unroll
        for (int jj = 0; jj < 4; ++jj) {
            const int t = jj * 16 + l15;
            const float po = pov[t];
            float4 o4;
            o4.x = po * acc[jj][0] + acg[jj][0];
            o4.y = po * acc[jj][1] + acg[jj][1];
            o4.z = po * acc[jj][2] + acg[jj][2];
            o4.w = po * acc[jj][3] + acg[jj][3];
            *(float4*)(Ot + t * 132 + dvt * 16 + lq * 4) = o4;
        }
    }
    __syncthreads();

    const int d = l * 2;
    const float lg0 = lng[d], lg1 = lng[d + 1];
    const float lb0 = lnb[d], lb1 = lnb[d + 1];
    const size_t btbase = (size_t)b * TSEQ + t0 + wv * 16;
#pragma unroll 1
    for (int rr = 0; rr < 16; ++rr) {
        const int t = wv * 16 + rr;
        float2 xv = *(const float2*)(Ot + t * 132 + d);
        float s = xv.x + xv.y;
#pragma unroll
        for (int m = 32; m; m >>= 1) s += __shfl_xor(s, m);
        const float mu = s * (1.f / 128.f);
        const float d0 = xv.x - mu, d1 = xv.y - mu;
        float v = d0 * d0 + d1 * d1;
#pragma unroll
        for (int m = 32; m; m >>= 1) v += __shfl_xor(v, m);
        const float inv = rsqrtf(v * (1.f / 128.f) + 1e-5f);
        const float* gp = g_lin + (btbase + rr) * HID_ + h * DV;
        const float g0 = sig_(gp[d]), g1 = sig_(gp[d + 1]);
        const float y0 = (d0 * inv * lg0 + lb0) * g0;
        const float y1 = (d1 * inv * lg1 + lb1) * g1;
        *(uint*)(ogb + (btbase + rr) * HID_ + h * DV + d) = pk2(y0, y1);
    }
}

extern "C" void kernel_launch(void* const* d_in, const int* in_sizes, int n_in,
                              void* d_out, int out_size, void* d_ws, size_t ws_size,
                              hipStream_t stream)
{
    const float* x   = (const float*)d_in[0];
    const float* Wq  = (const float*)d_in[1];
    const float* Wk  = (const float*)d_in[2];
    const float* Wv  = (const float*)d_in[3];
    const float* cqw = (const float*)d_in[4];
    const float* cqb = (const float*)d_in[5];
    const float* ckw = (const float*)d_in[6];
    const float* ckb = (const float*)d_in[7];
    const float* cvw = (const float*)d_in[8];
    const float* cvb = (const float*)d_in[9];
    const float* Wa  = (const float*)d_in[10];
    const float* ba  = (const float*)d_in[11];
    const float* Wb  = (const float*)d_in[12];
    const float* bb  = (const float*)d_in[13];
    const float* Wg  = (const float*)d_in[14];
    const float* Wo  = (const float*)d_in[15];
    const float* lng = (const float*)d_in[16];
    const float* lnb = (const float*)d_in[17];
    float* out = (float*)d_out;
    float* ws  = (float*)d_ws;

    float* q_lin = ws;                       // f32; dead after stageprep; ogb reuses
    float* k_lin = ws + 1 * (size_t)SZf;     // f32; dead after stageprep; WoT reuses
    float* v_lin = ws + 2 * (size_t)SZf;     // f32; dead after stageprep
    float* g_lin = ws + 3 * (size_t)SZf;     // read by k_out
    float* o_buf = ws + 4 * (size_t)SZf;     // WT4 -> conv scratch -> Sst
    float* aT    = ws + 5 * (size_t)SZf;
    float* bT    = aT + 16 * TSEQ;
    float* pug   = bT + 16 * TSEQ;
    float* pog   = pug + 256 * 64;
    float* cgd   = pog + 256 * 64;
    float* dtg   = cgd + 256 * 64;

    float*  tail = ws + 5 * (size_t)SZf + 131072;
    ushort* Kst  = (ushort*)tail;                    // 4MB
    ushort* Qst  = Kst + (size_t)256 * 8192;         // 4MB
    ushort* xbf  = Qst + (size_t)256 * 8192;         // 4MB; dead after gemm4
    ushort* Vst  = xbf;                              // reuse: written by stageprep
    ushort* KTst = xbf + (size_t)256 * 8192;         // 4MB

    ushort* WT4 = (ushort*)o_buf;            // dead after gemm4
    ushort* WoT = (ushort*)k_lin;            // written after stageprep
    ushort* ogb = (ushort*)q_lin;            // bf16 LN output (4MB)
    ushort* Sst = (ushort*)o_buf;            // 8MB: 256 x [128][128] bf16
    ushort* Mg  = (ushort*)out;              // 2MB
    ushort* Gg  = Mg + (size_t)256 * 4096;   // 2MB
    ushort* Wst = Gg + (size_t)256 * 4096;   // 4MB -> fills d_out exactly

    k_x2bf<<<1024, 256, 0, stream>>>(x, xbf);
    k_wT<<<dim3(16, 16, 4), 256, 0, stream>>>(Wq, Wk, Wv, Wg, WT4);
    k_gemm4<<<dim3(8, 16, 4), 256, 0, stream>>>(xbf, WT4, ws);
    k_ab<<<512, 256, 0, stream>>>(x, Wa, ba, Wb, bb, aT, bT);
    k_conv_save<<<dim3(15, 2, 3), 256, 0, stream>>>(q_lin, k_lin, v_lin, o_buf);
    k_conv_apply<<<dim3(64, 2, 3), 256, 0, stream>>>(q_lin, k_lin, v_lin, o_buf,
                                                     cqw, cqb, ckw, ckb, cvw, cvb);
    k_stageprep<<<256, 256, 0, stream>>>(k_lin, q_lin, v_lin, aT, bT,
                                         Kst, Qst, Vst, KTst, Mg, Gg,
                                         pug, pog, cgd, dtg);
    k_wT<<<dim3(16, 16, 1), 256, 0, stream>>>(Wo, Wo, Wo, Wo, WoT);
    k_scan2<<<32, 256, 0, stream>>>(Kst, KTst, Vst, Mg, pug, cgd, dtg, Sst, Wst);
    k_out<<<256, 256, 0, stream>>>(Sst, Qst, Gg, Wst, pog, g_lin, lng, lnb, ogb);
    k_gemm1<<<dim3(8, 16), 256, 0, stream>>>(ogb, WoT, out);
}

// Round 14
// 217.660 us; speedup vs baseline: 1.5420x; 1.0628x over previous
//
#include <hip/hip_runtime.h>

#define TSEQ 1024
#define HID_ 1024
#define NH 8
#define DK 128
#define DV 128
#define ROWS 2048               // B*T
#define SZf (ROWS * HID_)       // floats per [2048,1024] matrix
#define LCH 64                  // scan chunk length
#define NCK 16                  // chunks per (b,h)
#define KSTR 136                // bf16 LDS stride for [64][128] tiles
#define ESTR 65

typedef __attribute__((ext_vector_type(8))) short short8;
typedef __attribute__((ext_vector_type(4))) float f32x4;
#define MFMA __builtin_amdgcn_mfma_f32_16x16x32_bf16

__device__ __forceinline__ float sig_(float x) { return 1.f / (1.f + __expf(-x)); }

__device__ __forceinline__ ushort f2bf(float f) {   // RNE f32->bf16
    unsigned int u = __builtin_bit_cast(unsigned int, f);
    u += 0x7FFF + ((u >> 16) & 1);
    return (ushort)(u >> 16);
}
__device__ __forceinline__ float bf2f(ushort u) {
    return __builtin_bit_cast(float, ((unsigned int)u) << 16);
}
__device__ __forceinline__ unsigned int pk2(float lo, float hi) {
    return (unsigned int)f2bf(lo) | ((unsigned int)f2bf(hi) << 16);
}

// async global->LDS, 16B per lane; dst = wave-uniform base (+lane*16 by HW)
__device__ __forceinline__ void gload16(const void* g, void* l) {
    __builtin_amdgcn_global_load_lds(
        (const __attribute__((address_space(1))) unsigned int*)g,
        (__attribute__((address_space(3))) unsigned int*)l, 16, 0, 0);
}

// ---------------- x -> bf16 ----------------
__global__ __launch_bounds__(256)
void k_x2bf(const float* __restrict__ x, ushort* __restrict__ xb)
{
    const size_t i8 = (size_t)blockIdx.x * 256 + threadIdx.x;   // grid 1024
    float4 v0 = *(const float4*)(x + i8 * 8);
    float4 v1 = *(const float4*)(x + i8 * 8 + 4);
    uint4 o;
    o.x = pk2(v0.x, v0.y); o.y = pk2(v0.z, v0.w);
    o.z = pk2(v1.x, v1.y); o.w = pk2(v1.z, v1.w);
    *(uint4*)(xb + i8 * 8) = o;
}

// ---------------- weight transpose+convert: W f32 [K][N] -> WT bf16 [N][K] ----
__global__ __launch_bounds__(256)
void k_wT(const float* __restrict__ s0, const float* __restrict__ s1,
          const float* __restrict__ s2, const float* __restrict__ s3,
          ushort* __restrict__ dst)
{
    const int z = blockIdx.z;
    const float* W = (z == 0) ? s0 : (z == 1) ? s1 : (z == 2) ? s2 : s3;
    ushort* WT = dst + (size_t)z * (1024 * 1024);
    __shared__ float t[64][65];
    const int n0 = blockIdx.x * 64, k0 = blockIdx.y * 64;
    const int rr = threadIdx.x >> 4, cc = threadIdx.x & 15;
#pragma unroll
    for (int i = 0; i < 4; ++i) {
        const int row = i * 16 + rr;
        float4 v = *(const float4*)(W + (size_t)(k0 + row) * 1024 + n0 + cc * 4);
        t[row][cc * 4 + 0] = v.x; t[row][cc * 4 + 1] = v.y;
        t[row][cc * 4 + 2] = v.z; t[row][cc * 4 + 3] = v.w;
    }
    __syncthreads();
#pragma unroll
    for (int i = 0; i < 4; ++i) {
        const int n = i * 16 + rr;
        const int kc = cc * 4;
        ushort4 o;
        o.x = f2bf(t[kc + 0][n]); o.y = f2bf(t[kc + 1][n]);
        o.z = f2bf(t[kc + 2][n]); o.w = f2bf(t[kc + 3][n]);
        *(ushort4*)(WT + (size_t)(n0 + n) * 1024 + k0 + kc) = o;
    }
}

// ---- bf16 MFMA GEMM: BK=64, global_load_lds + XOR chunk-swizzle (T2, #21) ---
// LDS [128][64] bf16 (128B rows). Physical 16B slot (row,p) holds global chunk
// (row, p^(row&7)); read of logical chunk c uses p=c^(row&7) -> banks 4*p span
// all 32 banks (b128 throughput floor, no conflict). Source-side swizzle only.
__device__ __forceinline__ void gemm_tile_mfma(const ushort* __restrict__ A,
                                               const ushort* __restrict__ BT,
                                               float* __restrict__ C,
                                               int brow, int bcol)
{
    __shared__ ushort As[128 * 64];
    __shared__ ushort Bs[128 * 64];
    const int tid  = threadIdx.x;
    const int lane = tid & 63;
    const int wv   = tid >> 6;
    const int wm   = (wv >> 1) * 64;
    const int wn   = (wv & 1) * 64;
    const int l15  = lane & 15;
    const int lq   = lane >> 4;

    f32x4 acc[4][4];
#pragma unroll
    for (int i = 0; i < 4; ++i)
#pragma unroll
        for (int j = 0; j < 4; ++j)
#pragma unroll
            for (int e = 0; e < 4; ++e) acc[i][j][e] = 0.f;

    for (int k0 = 0; k0 < 1024; k0 += 64) {
        __syncthreads();                   // prior frags consumed
#pragma unroll
        for (int j = 0; j < 4; ++j) {
            const int idx  = j * 256 + tid;
            const int row  = idx >> 3;
            const int gcol = ((idx & 7) ^ (row & 7)) * 8;   // inverse swizzle
            const int ldst = (j * 256 + wv * 64) * 8;       // wave-uniform
            gload16(A  + (size_t)(brow + row) * 1024 + k0 + gcol, As + ldst);
            gload16(BT + (size_t)(bcol + row) * 1024 + k0 + gcol, Bs + ldst);
        }
        __syncthreads();                   // vmcnt drain -> data visible
#pragma unroll
        for (int kk = 0; kk < 2; ++kk) {
            short8 af[4], bf[4];
#pragma unroll
            for (int i = 0; i < 4; ++i) {
                const int ra = wm + i * 16 + l15;
                af[i] = *(const short8*)(As + ra * 64 + (((kk * 4 + lq) ^ (ra & 7)) * 8));
            }
#pragma unroll
            for (int j = 0; j < 4; ++j) {
                const int rb = wn + j * 16 + l15;
                bf[j] = *(const short8*)(Bs + rb * 64 + (((kk * 4 + lq) ^ (rb & 7)) * 8));
            }
#pragma unroll
            for (int i = 0; i < 4; ++i)
#pragma unroll
                for (int j = 0; j < 4; ++j)
                    acc[i][j] = MFMA(af[i], bf[j], acc[i][j], 0, 0, 0);
        }
    }
    const int l4 = lane >> 4;
#pragma unroll
    for (int i = 0; i < 4; ++i)
#pragma unroll
        for (int j = 0; j < 4; ++j)
#pragma unroll
            for (int r = 0; r < 4; ++r)
                C[(size_t)(brow + wm + i * 16 + l4 * 4 + r) * 1024 +
                  bcol + wn + j * 16 + l15] = acc[i][j][r];
}

__global__ __launch_bounds__(256)
void k_gemm4(const ushort* __restrict__ A, const ushort* __restrict__ WT,
             float* __restrict__ Cbase)
{
    const ushort* BT = WT + (size_t)blockIdx.z * (1024 * 1024);
    float* C = Cbase + (size_t)blockIdx.z * SZf;
    gemm_tile_mfma(A, BT, C, blockIdx.y * 128, blockIdx.x * 128);
}

__global__ __launch_bounds__(256)
void k_gemm1(const ushort* __restrict__ A, const ushort* __restrict__ BT,
             float* __restrict__ C)
{
    gemm_tile_mfma(A, BT, C, blockIdx.y * 128, blockIdx.x * 128);
}

// -------- alpha/beta small GEMM + sigmoid; writes TRANSPOSED [bh][t] --------
__global__ __launch_bounds__(256)
void k_ab(const float* __restrict__ x, const float* __restrict__ Wa,
          const float* __restrict__ ba, const float* __restrict__ Wb,
          const float* __restrict__ bb, float* __restrict__ aT,
          float* __restrict__ bT)
{
    const int r = blockIdx.x * 4 + (threadIdx.x >> 6);   // r = b*1024 + t
    const int lane = threadIdx.x & 63;
    const int b = r >> 10, t = r & 1023;
    const float* xr = x + (size_t)r * HID_;
    float acc[16];
#pragma unroll
    for (int n = 0; n < 16; ++n) acc[n] = 0.f;
    for (int c = lane; c < HID_; c += 64) {
        const float xv = xr[c];
        const float* wa = Wa + c * 8;
        const float* wb = Wb + c * 8;
#pragma unroll
        for (int n = 0; n < 8; ++n) {
            acc[n]     = fmaf(xv, wa[n], acc[n]);
            acc[8 + n] = fmaf(xv, wb[n], acc[8 + n]);
        }
    }
#pragma unroll
    for (int n = 0; n < 16; ++n) {
#pragma unroll
        for (int m = 32; m; m >>= 1) acc[n] += __shfl_xor(acc[n], m);
    }
    if (lane < 8) {
        aT[(size_t)(b * 8 + lane) * TSEQ + t] = sig_(acc[lane] + ba[lane]);
        bT[(size_t)(b * 8 + lane) * TSEQ + t] = sig_(acc[8 + lane] + bb[lane]);
    }
}

// ---- conv K=4 + SiLU (+scale), reads f32, writes bf16 STAGED layouts -------
// grid (32 = 16j x 2cg, 2 b, 3 z); thread owns 2 channels (cg covers 512 each).
// z=0: q->Qst [cid][t][dk]; z=1: k->Kst (scaled); z=2: v->Vrm row-major bf16.
__global__ __launch_bounds__(256)
void k_conv(const float* __restrict__ qf, const float* __restrict__ kf,
            const float* __restrict__ vf,
            const float* __restrict__ wq, const float* __restrict__ bq,
            const float* __restrict__ wk, const float* __restrict__ bk,
            const float* __restrict__ wv, const float* __restrict__ bv,
            ushort* __restrict__ Qst, ushort* __restrict__ Kst,
            ushort* __restrict__ Vrm)
{
    const int j = blockIdx.x >> 1, cg = blockIdx.x & 1;
    const int b = blockIdx.y, z = blockIdx.z;
    const float* src  = (z == 0) ? qf : (z == 1) ? kf : vf;
    const float* w    = (z == 0) ? wq : (z == 1) ? wk : wv;
    const float* bias = (z == 0) ? bq : (z == 1) ? bk : bv;
    const float scale = (z == 1) ? 0.08838834764831845f : 1.f;
    const int c2 = cg * 512 + threadIdx.x * 2;
    const float w0a = w[c2 * 4],     w1a = w[c2 * 4 + 1], w2a = w[c2 * 4 + 2], w3a = w[c2 * 4 + 3];
    const float w0b = w[c2 * 4 + 4], w1b = w[c2 * 4 + 5], w2b = w[c2 * 4 + 6], w3b = w[c2 * 4 + 7];
    const float bsa = bias[c2], bsb = bias[c2 + 1];
    float ya0 = 0.f, ya1 = 0.f, ya2 = 0.f, yb0 = 0.f, yb1 = 0.f, yb2 = 0.f;
    if (j > 0) {
#pragma unroll
        for (int i = 0; i < 3; ++i) {
            float2 t = *(const float2*)(src + (size_t)(b * TSEQ + j * 64 - 3 + i) * HID_ + c2);
            if (i == 0) { ya0 = t.x; yb0 = t.y; }
            else if (i == 1) { ya1 = t.x; yb1 = t.y; }
            else { ya2 = t.x; yb2 = t.y; }
        }
    }
    const int h = c2 >> 7, dk = c2 & 127;
    const int cid = (b * 8 + h) * 16 + j;
    ushort* dst = (z == 0) ? Qst : Kst;
#pragma unroll 4
    for (int tl = 0; tl < 64; ++tl) {
        float2 xv = *(const float2*)(src + (size_t)(b * TSEQ + j * 64 + tl) * HID_ + c2);
        float a0 = fmaf(w0a, ya0, fmaf(w1a, ya1, fmaf(w2a, ya2, fmaf(w3a, xv.x, bsa))));
        float a1 = fmaf(w0b, yb0, fmaf(w1b, yb1, fmaf(w2b, yb2, fmaf(w3b, xv.y, bsb))));
        const float s0 = a0 * sig_(a0) * scale;
        const float s1 = a1 * sig_(a1) * scale;
        const uint p = pk2(s0, s1);
        if (z < 2) *(uint*)(dst + (size_t)cid * 8192 + tl * 128 + dk) = p;
        else       *(uint*)(Vrm + (size_t)(b * TSEQ + j * 64 + tl) * HID_ + c2) = p;
        ya0 = ya1; ya1 = ya2; ya2 = xv.x;
        yb0 = yb1; yb1 = yb2; yb2 = xv.y;
    }
}

// ======= k_stageprep: KT (pre-scaled by cv) + V^T + M, G, decays per chunk ===
__global__ __launch_bounds__(256)
void k_stageprep(const ushort* __restrict__ Kst, const ushort* __restrict__ Qst,
                 const ushort* __restrict__ Vrm,
                 const float* __restrict__ aT, const float* __restrict__ bT,
                 ushort* __restrict__ KTst, ushort* __restrict__ VstT,
                 ushort* __restrict__ Mg, ushort* __restrict__ Gg,
                 float* __restrict__ pug, float* __restrict__ pog,
                 float* __restrict__ dtotg)
{
    const int cid = blockIdx.x;          // bh*16 + c
    const int bh = cid >> 4, c = cid & 15;
    const int b = bh >> 3, h = bh & 7;
    const int tid = threadIdx.x;
    const int t0 = c * LCH;

    __shared__ ushort Kb[64 * KSTR], Qb[64 * KSTR];
    __shared__ ushort Vl[128 * 72];
    __shared__ float Ef[64 * ESTR];
    __shared__ float Mf[64 * ESTR];
    __shared__ float cums[64], bv[64];

    if (tid < 64) {
        const float a = aT[(size_t)bh * TSEQ + t0 + tid];
        bv[tid] = bT[(size_t)bh * TSEQ + t0 + tid];
        float cs = __logf(a);
#pragma unroll
        for (int d = 1; d < 64; d <<= 1) {
            float pv = __shfl_up(cs, d);
            if (tid >= d) cs += pv;
        }
        cums[tid] = cs;
    }
    const size_t go = (size_t)cid * 8192;
#pragma unroll
    for (int j = 0; j < 4; ++j) {
        const int i16 = tid + j * 256;
        const int row = i16 >> 4, col = (i16 & 15) * 8;
        *(uint4*)(Kb + row * KSTR + col) = *(const uint4*)(Kst + go + i16 * 8);
        *(uint4*)(Qb + row * KSTR + col) = *(const uint4*)(Qst + go + i16 * 8);
    }
    // V: bf16 row-major -> Vl [dv][t]
#pragma unroll
    for (int j = 0; j < 4; ++j) {
        const int i16 = tid + j * 256;                   // 0..1023
        const int row = i16 >> 4, c8 = (i16 & 15) * 8;
        ushort tmp[8];
        *(uint4*)tmp = *(const uint4*)(Vrm + (size_t)(b * TSEQ + t0 + row) * HID_ + h * DV + c8);
#pragma unroll
        for (int e = 0; e < 8; ++e)
            Vl[(c8 + e) * 72 + row] = tmp[e];
    }
    __syncthreads();

    // V^T dump + KT dump (pre-scaled by cv[t] = exp(cums[63]-cums[t]))
    const float ctop = cums[63];
#pragma unroll
    for (int j = 0; j < 4; ++j) {
        const int idx = tid + j * 256;
        const int dv = idx >> 3, tq = (idx & 7) * 8;
        *(uint4*)(VstT + go + dv * 64 + tq) = *(const uint4*)(Vl + dv * 72 + tq);
        const int dk = idx >> 3, tt = (idx & 7) * 8;
        ushort tmp[8];
#pragma unroll
        for (int e = 0; e < 8; ++e)
            tmp[e] = f2bf(bf2f(Kb[(tt + e) * KSTR + dk]) * __expf(ctop - cums[tt + e]));
        *(uint4*)(KTst + go + dk * 64 + tt) = *(uint4*)tmp;
    }

    // grams
    const int wv = tid >> 6, l = tid & 63, l15 = l & 15, lq = l >> 4;
    const int k8o = lq * 8;
    f32x4 accK[4], accQ4[4];
#pragma unroll
    for (int j = 0; j < 4; ++j) {
        accK[j] = f32x4{0.f, 0.f, 0.f, 0.f};
        accQ4[j] = f32x4{0.f, 0.f, 0.f, 0.f};
    }
#pragma unroll
    for (int kk = 0; kk < 4; ++kk) {
        short8 aK = *(const short8*)(Kb + (wv * 16 + l15) * KSTR + kk * 32 + k8o);
        short8 aQ = *(const short8*)(Qb + (wv * 16 + l15) * KSTR + kk * 32 + k8o);
#pragma unroll
        for (int js = 0; js < 4; ++js) {
            short8 bK = *(const short8*)(Kb + (js * 16 + l15) * KSTR + kk * 32 + k8o);
            accK[js]  = MFMA(aK, bK, accK[js], 0, 0, 0);
            accQ4[js] = MFMA(aQ, bK, accQ4[js], 0, 0, 0);
        }
    }
    ushort* Gc = Gg + (size_t)cid * 4096;
#pragma unroll
    for (int js = 0; js < 4; ++js) {
#pragma unroll
        for (int r = 0; r < 4; ++r) {
            const int t = wv * 16 + lq * 4 + r;
            const int s = js * 16 + l15;
            const float cp = (t > 0) ? cums[t - 1] : 0.f;
            Ef[t * ESTR + s] = (s < t) ? __expf(cp - cums[s]) * accK[js][r] : 0.f;
            const float gv = (s <= t) ? __expf(cums[t] - cums[s]) * accQ4[js][r] : 0.f;
            Gc[t * 64 + s] = f2bf(gv);
        }
    }
    __syncthreads();

    if (tid < 64) {                     // M-solve: lane s owns column s
        const int s = tid;
        for (int r = 0; r < 64; ++r) Mf[r * ESTR + s] = 0.f;
        Mf[s * ESTR + s] = bv[s];
        for (int t = 1; t < 64; ++t) {
            float s0 = 0.f, s1 = 0.f;
            int r = 0;
            for (; r + 1 < t; r += 2) {
                s0 = fmaf(Ef[t * ESTR + r],     Mf[r * ESTR + s],       s0);
                s1 = fmaf(Ef[t * ESTR + r + 1], Mf[(r + 1) * ESTR + s], s1);
            }
            if (r < t) s0 = fmaf(Ef[t * ESTR + r], Mf[r * ESTR + s], s0);
            if (s < t) Mf[t * ESTR + s] = -bv[t] * (s0 + s1);
        }
    }
    __syncthreads();
    ushort* Mc = Mg + (size_t)cid * 4096;
#pragma unroll
    for (int j = 0; j < 16; ++j) {
        const int e = tid + j * 256;
        Mc[e] = f2bf(Mf[(e >> 6) * ESTR + (e & 63)]);
    }
    if (tid < 64) {
        const float cp = (tid > 0) ? cums[tid - 1] : 0.f;
        pug[cid * 64 + tid] = __expf(cp);
        pog[cid * 64 + tid] = __expf(cums[tid]);
        if (tid == 0) dtotg[cid] = __expf(cums[63]);
    }
}

// ===== kernel S (serial): swapped-operand chain; KT pre-scaled; 2 barriers ===
__global__ __launch_bounds__(256)
void k_scan2(const ushort* __restrict__ Kst, const ushort* __restrict__ KTst,
             const ushort* __restrict__ VstT, const ushort* __restrict__ Mg,
             const float* __restrict__ pug, const float* __restrict__ dtg,
             ushort* __restrict__ Sst, ushort* __restrict__ Wst)
{
    const int blk = blockIdx.x;          // bh*2 + half
    const int bh = blk >> 1, half = blk & 1;
    const int tid = threadIdx.x;
    const int wv = tid >> 6, l = tid & 63, l15 = l & 15, lq = l >> 4;
    const int k8o = lq * 8;
    const int dvw = wv * 16;

    __shared__ ushort Kb[64 * KSTR];
    __shared__ ushort KTb[128 * 72];
    __shared__ ushort Mb[64 * 72];
    __shared__ ushort Vb[64 * 72];
    __shared__ ushort Shb[64 * KSTR], Slb[64 * KSTR];
    __shared__ ushort Yb[64 * 72], Wb[64 * 72];
    __shared__ float puv[64], dts[1];

    f32x4 accS[8];
#pragma unroll
    for (int m = 0; m < 8; ++m) accS[m] = f32x4{0.f, 0.f, 0.f, 0.f};

    uint4 rk[4], rkt[4], rm[2], rv[2];
    float rpu = 0.f, rdt = 0.f;

    auto LOADC = [&](int cc) {
        const int cid = bh * 16 + cc;
        const size_t go = (size_t)cid * 8192;
#pragma unroll
        for (int j = 0; j < 4; ++j) {
            rk[j]  = *(const uint4*)(Kst  + go + (tid + j * 256) * 8);
            rkt[j] = *(const uint4*)(KTst + go + (tid + j * 256) * 8);
        }
#pragma unroll
        for (int j = 0; j < 2; ++j) {
            rm[j] = *(const uint4*)(Mg + (size_t)cid * 4096 + (tid + j * 256) * 8);
            rv[j] = *(const uint4*)(VstT + go + half * 4096 + (tid + j * 256) * 8);
        }
        if (tid < 64) {
            rpu = pug[cid * 64 + tid];
            if (tid == 0) rdt = dtg[cid];
        }
    };
    auto WRITEC = [&]() {
#pragma unroll
        for (int j = 0; j < 4; ++j) {
            const int i16 = tid + j * 256;
            *(uint4*)(Kb  + (i16 >> 4) * KSTR + (i16 & 15) * 8) = rk[j];
            *(uint4*)(KTb + (i16 >> 3) * 72   + (i16 & 7) * 8)  = rkt[j];
        }
#pragma unroll
        for (int j = 0; j < 2; ++j) {
            const int i8 = tid + j * 256;
            *(uint4*)(Mb + (i8 >> 3) * 72 + (i8 & 7) * 8) = rm[j];
            *(uint4*)(Vb + (i8 >> 3) * 72 + (i8 & 7) * 8) = rv[j];
        }
        if (tid < 64) {
            puv[tid] = rpu;
            if (tid == 0) dts[0] = rdt;
        }
    };

    LOADC(0); WRITEC();
    __syncthreads();

    for (int c = 0; c < NCK; ++c) {
        if (c + 1 < NCK) LOADC(c + 1);

        // ---- B: state (S^T acc) -> Shb/Slb [dv][dk] via b64 writes
#pragma unroll
        for (int m = 0; m < 8; ++m) {
            ushort h4[4], l4v[4];
#pragma unroll
            for (int r = 0; r < 4; ++r) {
                const float sv = accS[m][r];
                const ushort hi = f2bf(sv);
                h4[r] = hi;
                l4v[r] = f2bf(sv - bf2f(hi));
            }
            *(uint2*)(Shb + (dvw + l15) * KSTR + m * 16 + lq * 4) = *(uint2*)h4;
            *(uint2*)(Slb + (dvw + l15) * KSTR + m * 16 + lq * 4) = *(uint2*)l4v;
        }
        // ---- C': U^T = K.S^T (compensated)
        f32x4 accU[4];
#pragma unroll
        for (int jj = 0; jj < 4; ++jj) accU[jj] = f32x4{0.f, 0.f, 0.f, 0.f};
#pragma unroll
        for (int kk = 0; kk < 4; ++kk) {
            short8 sh = *(const short8*)(Shb + (dvw + l15) * KSTR + kk * 32 + k8o);
            short8 sl = *(const short8*)(Slb + (dvw + l15) * KSTR + kk * 32 + k8o);
#pragma unroll
            for (int jj = 0; jj < 4; ++jj) {
                short8 ka = *(const short8*)(Kb + (jj * 16 + l15) * KSTR + kk * 32 + k8o);
                accU[jj] = MFMA(ka, sh, accU[jj], 0, 0, 0);
                accU[jj] = MFMA(ka, sl, accU[jj], 0, 0, 0);
            }
        }
        // ---- D': Y[dv][t] = V - pu (.) U (lane-local b64)
#pragma unroll
        for (int jj = 0; jj < 4; ++jj) {
            float pu4[4];
            *(float4*)pu4 = *(const float4*)(puv + jj * 16 + lq * 4);
            ushort v4[4];
            *(uint2*)v4 = *(const uint2*)(Vb + (dvw + l15) * 72 + jj * 16 + lq * 4);
            ushort y4[4];
#pragma unroll
            for (int r = 0; r < 4; ++r)
                y4[r] = f2bf(bf2f(v4[r]) - pu4[r] * accU[jj][r]);
            *(uint2*)(Yb + (dvw + l15) * 72 + jj * 16 + lq * 4) = *(uint2*)y4;
        }
        // ---- E'': W^T = M.Y
        f32x4 accW[4];
#pragma unroll
        for (int jj = 0; jj < 4; ++jj) accW[jj] = f32x4{0.f, 0.f, 0.f, 0.f};
#pragma unroll
        for (int kk = 0; kk < 2; ++kk) {
            short8 yb = *(const short8*)(Yb + (dvw + l15) * 72 + kk * 32 + k8o);
#pragma unroll
            for (int jj = 0; jj < 4; ++jj) {
                short8 mf = *(const short8*)(Mb + (jj * 16 + l15) * 72 + kk * 32 + k8o);
                accW[jj] = MFMA(mf, yb, accW[jj], 0, 0, 0);
            }
        }
#pragma unroll
        for (int jj = 0; jj < 4; ++jj) {
            ushort w4[4];
#pragma unroll
            for (int r = 0; r < 4; ++r)
                w4[r] = f2bf(accW[jj][r]);
            *(uint2*)(Wb + (dvw + l15) * 72 + jj * 16 + lq * 4) = *(uint2*)w4;
        }
        // ---- G: S^T = dtot.S^T + KTc.W   (KT pre-scaled by cv)
        const float dt = dts[0];
#pragma unroll
        for (int m = 0; m < 8; ++m)
#pragma unroll
            for (int r = 0; r < 4; ++r) accS[m][r] *= dt;
#pragma unroll
        for (int kk = 0; kk < 2; ++kk) {
            short8 wc = *(const short8*)(Wb + (dvw + l15) * 72 + kk * 32 + k8o);
#pragma unroll
            for (int m = 0; m < 8; ++m) {
                short8 kt = *(const short8*)(KTb + (m * 16 + l15) * 72 + kk * 32 + k8o);
                accS[m] = MFMA(kt, wc, accS[m], 0, 0, 0);
            }
        }
        // ---- dumps (wave-local regions of Shb/Wb)
        {
            const int cid = bh * 16 + c;
#pragma unroll
            for (int j = 0; j < 4; ++j) {
                const int idx = l + j * 64;
                const int dvo = idx >> 4, ko = (idx & 15) * 8;
                *(uint4*)(Sst + (size_t)cid * 16384 +
                          (half * 64 + dvw + dvo) * 128 + ko) =
                    *(const uint4*)(Shb + (dvw + dvo) * KSTR + ko);
            }
#pragma unroll
            for (int j = 0; j < 2; ++j) {
                const int idx = l + j * 64;
                const int dvo = idx >> 3, t8 = (idx & 7) * 8;
                *(uint4*)(Wst + (size_t)cid * 8192 +
                          (half * 64 + dvw + dvo) * 64 + t8) =
                    *(const uint4*)(Wb + (dvw + dvo) * 72 + t8);
            }
        }
        __syncthreads();
        if (c + 1 < NCK) WRITEC();
        __syncthreads();
    }
}

// ===== kernel O (parallel): O = po (.) S.Q^T + G.W, fused LayerNorm + gate ====
__global__ __launch_bounds__(256)
void k_out(const ushort* __restrict__ Sst, const ushort* __restrict__ Qst,
           const ushort* __restrict__ Gg, const ushort* __restrict__ Wst,
           const float* __restrict__ pog, const float* __restrict__ g_lin,
           const float* __restrict__ lng, const float* __restrict__ lnb,
           ushort* __restrict__ ogb)
{
    const int cid = blockIdx.x;
    const int bh = cid >> 4, c = cid & 15;
    const int b = bh >> 3, h = bh & 7;
    const int t0 = c * LCH;
    const int tid = threadIdx.x;
    const int wv = tid >> 6, l = tid & 63, l15 = l & 15, lq = l >> 4;
    const int k8o = lq * 8;

    __shared__ ushort Sb[128 * KSTR];
    __shared__ ushort Qb[64 * KSTR];
    __shared__ ushort Gb[64 * 72];
    __shared__ ushort Wqb[128 * 72];
    __shared__ float  Ot[64 * 132];
    __shared__ float  pov[64];

#pragma unroll
    for (int j = 0; j < 8; ++j) {
        const int i16 = tid + j * 256;
        *(uint4*)(Sb + (i16 >> 4) * KSTR + (i16 & 15) * 8) =
            *(const uint4*)(Sst + (size_t)cid * 16384 + i16 * 8);
    }
#pragma unroll
    for (int j = 0; j < 4; ++j) {
        const int i16 = tid + j * 256;
        *(uint4*)(Qb + (i16 >> 4) * KSTR + (i16 & 15) * 8) =
            *(const uint4*)(Qst + (size_t)cid * 8192 + i16 * 8);
        const int i8 = i16;
        *(uint4*)(Wqb + (i8 >> 3) * 72 + (i8 & 7) * 8) =
            *(const uint4*)(Wst + (size_t)cid * 8192 + i8 * 8);
    }
#pragma unroll
    for (int j = 0; j < 2; ++j) {
        const int i8 = tid + j * 256;
        *(uint4*)(Gb + (i8 >> 3) * 72 + (i8 & 7) * 8) =
            *(const uint4*)(Gg + (size_t)cid * 4096 + i8 * 8);
    }
    if (tid < 64) pov[tid] = pog[cid * 64 + tid];
    __syncthreads();

#pragma unroll
    for (int i = 0; i < 2; ++i) {
        const int dvt = wv * 2 + i;
        f32x4 acc[4], acg[4];
#pragma unroll
        for (int jj = 0; jj < 4; ++jj) {
            acc[jj] = f32x4{0.f, 0.f, 0.f, 0.f};
            acg[jj] = f32x4{0.f, 0.f, 0.f, 0.f};
        }
#pragma unroll
        for (int kk = 0; kk < 4; ++kk) {
            short8 sa = *(const short8*)(Sb + (dvt * 16 + l15) * KSTR + kk * 32 + k8o);
#pragma unroll
            for (int jj = 0; jj < 4; ++jj) {
                short8 qb = *(const short8*)(Qb + (jj * 16 + l15) * KSTR + kk * 32 + k8o);
                acc[jj] = MFMA(sa, qb, acc[jj], 0, 0, 0);
            }
        }
#pragma unroll
        for (int kk = 0; kk < 2; ++kk) {
            short8 wa = *(const short8*)(Wqb + (dvt * 16 + l15) * 72 + kk * 32 + k8o);
#pragma unroll
            for (int jj = 0; jj < 4; ++jj) {
                short8 gb = *(const short8*)(Gb + (jj * 16 + l15) * 72 + kk * 32 + k8o);
                acg[jj] = MFMA(wa, gb, acg[jj], 0, 0, 0);
            }
        }
#pragma unroll
        for (int jj = 0; jj < 4; ++jj) {
            const int t = jj * 16 + l15;
            const float po = pov[t];
            float4 o4;
            o4.x = po * acc[jj][0] + acg[jj][0];
            o4.y = po * acc[jj][1] + acg[jj][1];
            o4.z = po * acc[jj][2] + acg[jj][2];
            o4.w = po * acc[jj][3] + acg[jj][3];
            *(float4*)(Ot + t * 132 + dvt * 16 + lq * 4) = o4;
        }
    }
    __syncthreads();

    const int d = l * 2;
    const float lg0 = lng[d], lg1 = lng[d + 1];
    const float lb0 = lnb[d], lb1 = lnb[d + 1];
    const size_t btbase = (size_t)b * TSEQ + t0 + wv * 16;
#pragma unroll 1
    for (int rr = 0; rr < 16; ++rr) {
        const int t = wv * 16 + rr;
        float2 xv = *(const float2*)(Ot + t * 132 + d);
        float s = xv.x + xv.y;
#pragma unroll
        for (int m = 32; m; m >>= 1) s += __shfl_xor(s, m);
        const float mu = s * (1.f / 128.f);
        const float d0 = xv.x - mu, d1 = xv.y - mu;
        float v = d0 * d0 + d1 * d1;
#pragma unroll
        for (int m = 32; m; m >>= 1) v += __shfl_xor(v, m);
        const float inv = rsqrtf(v * (1.f / 128.f) + 1e-5f);
        const float* gp = g_lin + (btbase + rr) * HID_ + h * DV;
        const float g0 = sig_(gp[d]), g1 = sig_(gp[d + 1]);
        const float y0 = (d0 * inv * lg0 + lb0) * g0;
        const float y1 = (d1 * inv * lg1 + lb1) * g1;
        *(uint*)(ogb + (btbase + rr) * HID_ + h * DV + d) = pk2(y0, y1);
    }
}

extern "C" void kernel_launch(void* const* d_in, const int* in_sizes, int n_in,
                              void* d_out, int out_size, void* d_ws, size_t ws_size,
                              hipStream_t stream)
{
    const float* x   = (const float*)d_in[0];
    const float* Wq  = (const float*)d_in[1];
    const float* Wk  = (const float*)d_in[2];
    const float* Wv  = (const float*)d_in[3];
    const float* cqw = (const float*)d_in[4];
    const float* cqb = (const float*)d_in[5];
    const float* ckw = (const float*)d_in[6];
    const float* ckb = (const float*)d_in[7];
    const float* cvw = (const float*)d_in[8];
    const float* cvb = (const float*)d_in[9];
    const float* Wa  = (const float*)d_in[10];
    const float* ba  = (const float*)d_in[11];
    const float* Wb  = (const float*)d_in[12];
    const float* bb  = (const float*)d_in[13];
    const float* Wg  = (const float*)d_in[14];
    const float* Wo  = (const float*)d_in[15];
    const float* lng = (const float*)d_in[16];
    const float* lnb = (const float*)d_in[17];
    float* out = (float*)d_out;
    float* ws  = (float*)d_ws;

    float* q_lin = ws;                       // f32; dead after conv; ogb+VstT reuse
    float* k_lin = ws + 1 * (size_t)SZf;     // f32; dead after conv; WoT reuses
    float* v_lin = ws + 2 * (size_t)SZf;     // f32; dead after conv
    float* g_lin = ws + 3 * (size_t)SZf;     // read by k_out
    float* o_buf = ws + 4 * (size_t)SZf;     // WT4 -> Sst
    float* aT    = ws + 5 * (size_t)SZf;
    float* bT    = aT + 16 * TSEQ;
    float* pug   = bT + 16 * TSEQ;
    float* pog   = pug + 256 * 64;
    float* dtg   = pog + 256 * 64;

    float*  tail = ws + 5 * (size_t)SZf + 131072;
    ushort* Kst  = (ushort*)tail;                    // 4MB (conv out)
    ushort* Qst  = Kst + (size_t)256 * 8192;         // 4MB (conv out)
    ushort* xbf  = Qst + (size_t)256 * 8192;         // 4MB; dead after gemm4
    ushort* Vrm  = xbf;                              // reuse: conv out, bf16 row-major
    ushort* KTst = xbf + (size_t)256 * 8192;         // 4MB (stageprep out)

    ushort* WT4  = (ushort*)o_buf;           // dead after gemm4
    ushort* WoT  = (ushort*)k_lin;           // written after conv
    ushort* ogb  = (ushort*)q_lin;           // bf16 LN output (4MB, lo half)
    ushort* VstT = (ushort*)q_lin + (size_t)2 * 1024 * 1024;  // 4MB, hi half
    ushort* Sst  = (ushort*)o_buf;           // 8MB
    ushort* Mg   = (ushort*)out;             // 2MB
    ushort* Gg   = Mg + (size_t)256 * 4096;  // 2MB
    ushort* Wst  = Gg + (size_t)256 * 4096;  // 4MB -> fills d_out exactly

    k_x2bf<<<1024, 256, 0, stream>>>(x, xbf);
    k_wT<<<dim3(16, 16, 4), 256, 0, stream>>>(Wq, Wk, Wv, Wg, WT4);
    k_gemm4<<<dim3(8, 16, 4), 256, 0, stream>>>(xbf, WT4, ws);
    k_ab<<<512, 256, 0, stream>>>(x, Wa, ba, Wb, bb, aT, bT);
    k_conv<<<dim3(32, 2, 3), 256, 0, stream>>>(q_lin, k_lin, v_lin,
                                               cqw, cqb, ckw, ckb, cvw, cvb,
                                               Qst, Kst, Vrm);
    k_wT<<<dim3(16, 16, 1), 256, 0, stream>>>(Wo, Wo, Wo, Wo, WoT);
    k_stageprep<<<256, 256, 0, stream>>>(Kst, Qst, Vrm, aT, bT,
                                         KTst, VstT, Mg, Gg, pug, pog, dtg);
    k_scan2<<<32, 256, 0, stream>>>(Kst, KTst, VstT, Mg, pug, dtg, Sst, Wst);
    k_out<<<256, 256, 0, stream>>>(Sst, Qst, Gg, Wst, pog, g_lin, lng, lnb, ogb);
    k_gemm1<<<dim3(8, 16), 256, 0, stream>>>(ogb, WoT, out);
}